// Round 13
// baseline (338.435 us; speedup 1.0000x reference)
//
#include <hip/hip_runtime.h>

#define LR 0.01f

// Problem constants (from reference setup_inputs): B=4, S=2048, D=1024, Ds=256
constexpr int Bc  = 4;
constexpr int Sc  = 2048;
constexpr int Dc  = 1024;
constexpr int Dsc = 256;

// ---------------------------------------------------------------------------
// Tiled fp32 GEMM (v10, verified): A-tile transposed in LDS, float4 reads,
// float4 epilogue.
// ---------------------------------------------------------------------------
__global__ __launch_bounds__(256) void gemm_bias(
    const float* __restrict__ A, const float* __restrict__ Bm,
    const float* __restrict__ bias, const float* __restrict__ resid,
    float* __restrict__ C, int M, int N, int K) {
  constexpr int BM = 64, BN = 64, BK = 16;
  __shared__ float As[BM][BK + 4];
  __shared__ float Bs[BK][BN + 4];

  const int bm = blockIdx.x * BM;
  const int bn = blockIdx.y * BN;
  const int tx = threadIdx.x & 15;
  const int ty = threadIdx.x >> 4;

  float acc[4][4] = {};

  for (int k0 = 0; k0 < K; k0 += BK) {
#pragma unroll
    for (int qq = 0; qq < 4; ++qq) {
      int m = ty + 16 * qq;
      As[m][tx] = A[(size_t)(bm + m) * K + k0 + tx];
    }
#pragma unroll
    for (int qq = 0; qq < 4; ++qq) {
      int i = threadIdx.x + 256 * qq;
      int k = i >> 6, n = i & 63;
      Bs[k][n] = Bm[(size_t)(k0 + k) * N + bn + n];
    }
    __syncthreads();
#pragma unroll
    for (int k4 = 0; k4 < BK; k4 += 4) {
      float4 a0 = *(const float4*)&As[ty * 4 + 0][k4];
      float4 a1 = *(const float4*)&As[ty * 4 + 1][k4];
      float4 a2 = *(const float4*)&As[ty * 4 + 2][k4];
      float4 a3 = *(const float4*)&As[ty * 4 + 3][k4];
      float4 b0 = *(const float4*)&Bs[k4 + 0][tx * 4];
      float4 b1 = *(const float4*)&Bs[k4 + 1][tx * 4];
      float4 b2 = *(const float4*)&Bs[k4 + 2][tx * 4];
      float4 b3 = *(const float4*)&Bs[k4 + 3][tx * 4];
#define ROWI(AI)                                          \
      acc[AI][0] = fmaf(a##AI.x, b0.x, acc[AI][0]);       \
      acc[AI][1] = fmaf(a##AI.x, b0.y, acc[AI][1]);       \
      acc[AI][2] = fmaf(a##AI.x, b0.z, acc[AI][2]);       \
      acc[AI][3] = fmaf(a##AI.x, b0.w, acc[AI][3]);       \
      acc[AI][0] = fmaf(a##AI.y, b1.x, acc[AI][0]);       \
      acc[AI][1] = fmaf(a##AI.y, b1.y, acc[AI][1]);       \
      acc[AI][2] = fmaf(a##AI.y, b1.z, acc[AI][2]);       \
      acc[AI][3] = fmaf(a##AI.y, b1.w, acc[AI][3]);       \
      acc[AI][0] = fmaf(a##AI.z, b2.x, acc[AI][0]);       \
      acc[AI][1] = fmaf(a##AI.z, b2.y, acc[AI][1]);       \
      acc[AI][2] = fmaf(a##AI.z, b2.z, acc[AI][2]);       \
      acc[AI][3] = fmaf(a##AI.z, b2.w, acc[AI][3]);       \
      acc[AI][0] = fmaf(a##AI.w, b3.x, acc[AI][0]);       \
      acc[AI][1] = fmaf(a##AI.w, b3.y, acc[AI][1]);       \
      acc[AI][2] = fmaf(a##AI.w, b3.z, acc[AI][2]);       \
      acc[AI][3] = fmaf(a##AI.w, b3.w, acc[AI][3]);
      ROWI(0) ROWI(1) ROWI(2) ROWI(3)
#undef ROWI
    }
    __syncthreads();
  }

  float4 bias4 = *(const float4*)&bias[bn + tx * 4];
#pragma unroll
  for (int i = 0; i < 4; ++i) {
    int m = bm + ty * 4 + i;
    float4 v;
    v.x = acc[i][0] + bias4.x;
    v.y = acc[i][1] + bias4.y;
    v.z = acc[i][2] + bias4.z;
    v.w = acc[i][3] + bias4.w;
    if (resid) {
      float4 r = *(const float4*)&resid[(size_t)m * N + bn + tx * 4];
      v.x += r.x; v.y += r.y; v.z += r.z; v.w += r.w;
    }
    *(float4*)&C[(size_t)m * N + bn + tx * 4] = v;
  }
}

// ---------------------------------------------------------------------------
// v14 scan: v13's math and per-wave code EXACTLY (verified), repartitioned as
// 512 blocks x 128 threads (2 waves, 2 columns each). LDS/block = 72KB ->
// TWO blocks co-resident per CU = two independent barrier domains. v13
// post-mortem: ~3900 cyc/chunk of diffuse stall (barrier skew, vmcnt
// handoff, lgkm waits, DPP hazards) hit all waves of the single lockstep
// block at once; a co-resident block absorbs it. Null result would mean
// per-CU-pipe bound -> next step is instruction-count reduction.
// ---------------------------------------------------------------------------

template <int CTRL, int RM>
__device__ __forceinline__ float dpp_sum(float v) {
  int moved = __builtin_amdgcn_update_dpp(0, __float_as_int(v), CTRL, RM, 0xF, false);
  return v + __int_as_float(moved);
}

__device__ __forceinline__ float rdlane(float v, int l) {
  return __int_as_float(__builtin_amdgcn_readlane(__float_as_int(v), l));
}

__device__ __forceinline__ void async_copy16(const float* g, float* l) {
  __builtin_amdgcn_global_load_lds(
      (const __attribute__((address_space(1))) unsigned int*)g,
      (__attribute__((address_space(3))) unsigned int*)l, 16, 0, 0);
}

constexpr int RCH = 32;        // rows per chunk
constexpr int NCH = Sc / RCH;  // 64 chunks

// MTg[bc][s*32+t] = M[t][s], M = (I + L)^{-1}, L[t][s] = LR*dot(f_t,f_s) s<t
__global__ __launch_bounds__(256) void gram_inv(const float* __restrict__ feat,
                                                float* __restrict__ MTg) {
  const int bc = blockIdx.x;  // 0..B*NCH-1
  __shared__ float Fl[32 * 260];
  __shared__ float Gl[32 * 32];
  __shared__ float Ml[32 * 32];
  const float* src = feat + (size_t)bc * RCH * Dsc;
  for (int i = threadIdx.x; i < 32 * 256; i += 256) {
    int r = i >> 8, cc = i & 255;
    Fl[r * 260 + cc] = src[i];
  }
  __syncthreads();
#pragma unroll
  for (int k2 = 0; k2 < 4; ++k2) {
    int idx = threadIdx.x + (k2 << 8);
    int t = idx >> 5, s = idx & 31;
    float sum = 0.f;
    if (s < t) {
      const float4* ft = (const float4*)&Fl[t * 260];
      const float4* fs = (const float4*)&Fl[s * 260];
#pragma unroll
      for (int i = 0; i < 64; ++i) {
        float4 a = ft[i], b = fs[i];
        sum = fmaf(a.x, b.x, sum); sum = fmaf(a.y, b.y, sum);
        sum = fmaf(a.z, b.z, sum); sum = fmaf(a.w, b.w, sum);
      }
      sum *= LR;
    }
    Gl[idx] = sum;  // L[t][s] (strict lower), 0 elsewhere
  }
  __syncthreads();
  // Forward substitution, column s per lane.
  if (threadIdx.x < 32) {
    const int s = threadIdx.x;
    for (int t = 0; t < 32; ++t) {
      float sum = 0.f;
      for (int u = 0; u < t; ++u)
        sum = fmaf(Gl[t * 32 + u], Ml[u * 32 + s], sum);
      Ml[t * 32 + s] = ((t == s) ? 1.f : 0.f) - sum;
    }
  }
  __syncthreads();
  float* dst = MTg + (size_t)bc * 1024;
#pragma unroll
  for (int k2 = 0; k2 < 4; ++k2) {
    int idx = threadIdx.x + (k2 << 8);
    int s = idx >> 5, t = idx & 31;
    dst[idx] = Ml[t * 32 + s];  // transposed store
  }
}

// X-macro row lists
#define ROWS_A(X) X(0) X(1) X(2) X(3) X(4) X(5) X(6) X(7)
#define ROWS_B(X) X(8) X(9) X(10) X(11) X(12) X(13) X(14) X(15)
#define ROWS_C(X) X(16) X(17) X(18) X(19) X(20) X(21) X(22) X(23)
#define ROWS_D(X) X(24) X(25) X(26) X(27) X(28) X(29) X(30) X(31)
#define ROWS_ALL(X) ROWS_A(X) ROWS_B(X) ROWS_C(X) ROWS_D(X)

__global__ __launch_bounds__(128, 1) void ttt_scan(
    const float* __restrict__ feat, const float* __restrict__ MTg,
    float* __restrict__ preds) {
  const int lane = threadIdx.x & 63;
  const int wave = threadIdx.x >> 6;   // 0..1
  const int lm = lane & 31;

  // XCD-locality swizzle for 512 blocks: XCDs {0,1}->b=0 ... {6,7}->b=3.
  const int bi  = blockIdx.x;                    // 0..511
  const int xcd = bi & 7;
  const int b   = xcd >> 1;                      // 0..3
  const int q   = ((bi >> 3) << 1) | (xcd & 1);  // 0..127 col-pair within b
  const int j   = (q << 1) | wave;               // 0..255

  __shared__ float ldsF[2][RCH * Dsc];  // 64 KB
  __shared__ float ldsM[2][1024];       // 8 KB  -> 72 KB/block, 2 blocks/CU

  const float* fb0 = feat + (size_t)b * Sc * Dsc;
  const float* Mg  = MTg + (size_t)b * NCH * 1024;
  float* pb0 = preds + (size_t)b * Sc * Dsc + j;

// 18 async loads per wave per stage: 16 feat rows + 2 quarters of M.
#define STAGE(BUF, C0)                                                    \
  {                                                                       \
    _Pragma("unroll")                                                     \
    for (int r_ = 0; r_ < 16; ++r_) {                                     \
      const int row_ = (wave << 4) | r_;                                  \
      async_copy16(fb0 + (size_t)((C0) * RCH + row_) * Dsc + (lane << 2), \
                   &ldsF[BUF][row_ * Dsc]);                               \
    }                                                                     \
    _Pragma("unroll")                                                     \
    for (int k_ = 0; k_ < 2; ++k_) {                                      \
      const int off_ = (wave << 9) | (k_ << 8);                           \
      async_copy16(Mg + (size_t)(C0) * 1024 + off_ + (lane << 2),         \
                   &ldsM[BUF][off_]);                                     \
    }                                                                     \
  }

#define DECLF(R) float4 F4_##R;
#define DECLD(R) float dsc_##R;

// One b128 per row: lane l holds f_R[4l..4l+3].
#define LOADF(R) F4_##R = *(const float4*)&pF[(R) * 256 + (lane << 2)];

// P0 for row R: dot(f_R, w) -> DPP reduce -> uniform d_R = p0 - f_R[j].
#define P0C(R)                                                                 \
  {                                                                            \
    float dd = fmaf(F4_##R.y, w4y, F4_##R.x * w4x) +                           \
               fmaf(F4_##R.w, w4w, F4_##R.z * w4z);                            \
    dd = dpp_sum<0x111, 0xF>(dd);                                              \
    dd = dpp_sum<0x112, 0xF>(dd);                                              \
    dd = dpp_sum<0x114, 0xF>(dd);                                              \
    dd = dpp_sum<0x118, 0xF>(dd);                                              \
    dd = dpp_sum<0x142, 0xA>(dd);                                              \
    dd = dpp_sum<0x143, 0xC>(dd);                                              \
    float p0_ = rdlane(dd, 63);                                                \
    float fj_ = rdlane(v_fjcol, (R));                                          \
    dsc_##R = p0_ - fj_;                                                       \
  }

// Matvec step s: e += M^T[s][lane] * d_s  (d_s uniform; no readlane).
#define MV(S, EK) e##EK = fmaf(pM[(S) * 32 + lm], dsc_##S, e##EK);

// acc += e_t * f_t (register-held rows; 4 independent chains).
#define ACCT(R)                                    \
  {                                                \
    float et_ = rdlane(v_e, (R));                  \
    accx = fmaf(et_, F4_##R.x, accx);              \
    accy = fmaf(et_, F4_##R.y, accy);              \
    accz = fmaf(et_, F4_##R.z, accz);              \
    accw = fmaf(et_, F4_##R.w, accw);              \
  }

  // Prologue: stage chunks 0,1; wait for chunk 0 (chunk 1's 18 may remain).
  STAGE(0, 0);
  STAGE(1, 1);
  asm volatile("s_waitcnt vmcnt(18)" ::: "memory");
  __builtin_amdgcn_s_barrier();
  __builtin_amdgcn_sched_barrier(0);

  float w4x = 0.f, w4y = 0.f, w4z = 0.f, w4w = 0.f;

#pragma unroll 1
  for (int c = 0; c < NCH; ++c) {
    const int cb = c & 1;
    const float* pF = &ldsF[cb][0];
    const float* pM = &ldsM[cb][0];

    ROWS_ALL(DECLF)
    ROWS_ALL(DECLD)
    float e0 = 0.f, e1 = 0.f, e2 = 0.f, e3 = 0.f;
    float accx = 0.f, accy = 0.f, accz = 0.f, accw = 0.f;

    // FJ column, one instruction (32-way conflict, latency hidden under the
    // b128 row loads).
    float v_fjcol = pF[lm * 256 + j];

    // Phase 1: loads one 8-row group ahead of P0 compute.
    ROWS_A(LOADF)
    ROWS_B(LOADF)
    __builtin_amdgcn_sched_barrier(0);
    ROWS_C(LOADF)
    ROWS_A(P0C)
    __builtin_amdgcn_sched_barrier(0);
    ROWS_D(LOADF)
    ROWS_B(P0C)
    __builtin_amdgcn_sched_barrier(0);
    ROWS_C(P0C)
    ROWS_D(P0C)

    // Phase 2: e = M d (d uniform scalars; 4 independent partial chains).
    MV(0, 0)  MV(1, 1)  MV(2, 2)  MV(3, 3)
    MV(4, 0)  MV(5, 1)  MV(6, 2)  MV(7, 3)
    MV(8, 0)  MV(9, 1)  MV(10, 2) MV(11, 3)
    MV(12, 0) MV(13, 1) MV(14, 2) MV(15, 3)
    MV(16, 0) MV(17, 1) MV(18, 2) MV(19, 3)
    MV(20, 0) MV(21, 1) MV(22, 2) MV(23, 3)
    MV(24, 0) MV(25, 1) MV(26, 2) MV(27, 3)
    MV(28, 0) MV(29, 1) MV(30, 2) MV(31, 3)
    float v_e = (e0 + e1) + (e2 + e3);

    // Phase 3: preds: p_t = e_t + f_t[j]  (lane t).
    if (lane < 32) pb0[(size_t)(c * RCH + lane) * Dsc] = v_e + v_fjcol;

    // Phase 4: acc = F^T e from register rows; one W update per chunk.
    ROWS_ALL(ACCT)
    w4x = fmaf(-LR, accx, w4x); w4y = fmaf(-LR, accy, w4y);
    w4z = fmaf(-LR, accz, w4z); w4w = fmaf(-LR, accw, w4w);

    // Handoff (proven): barrier -> stage c+2 over buf cb -> counted
    // vmcnt(18) (chunk c+1's 18 loads are older) -> barrier.
    __builtin_amdgcn_s_barrier();
    if (c + 2 < NCH) {
      STAGE(cb, c + 2);
      asm volatile("s_waitcnt vmcnt(18)" ::: "memory");
    } else {
      asm volatile("s_waitcnt vmcnt(0)" ::: "memory");
    }
    __builtin_amdgcn_s_barrier();
    __builtin_amdgcn_sched_barrier(0);
  }
#undef ACCT
#undef MV
#undef P0C
#undef LOADF
#undef DECLD
#undef DECLF
#undef STAGE
}

extern "C" void kernel_launch(void* const* d_in, const int* in_sizes, int n_in,
                              void* d_out, int out_size, void* d_ws, size_t ws_size,
                              hipStream_t stream) {
  const float* x  = (const float*)d_in[0];  // (B,S,D)
  const float* Wd = (const float*)d_in[1];  // (D,Ds)
  const float* bd = (const float*)d_in[2];  // (Ds)
  const float* Wu = (const float*)d_in[3];  // (Ds,D)
  const float* bu = (const float*)d_in[4];  // (D)
  float* out = (float*)d_out;               // (B,S,D)

  float* feat  = (float*)d_ws;                        // B*S*Ds f32 = 8 MB
  float* preds = feat + (size_t)Bc * Sc * Dsc;        // 8 MB
  float* MTg   = preds + (size_t)Bc * Sc * Dsc;       // B*NCH*1024 f32 = 1 MB

  const int M = Bc * Sc;  // 8192

  // feat = x @ W_down + b_down   (M=8192, N=256, K=1024)
  gemm_bias<<<dim3(M / 64, Dsc / 64), dim3(256), 0, stream>>>(
      x, Wd, bd, nullptr, feat, M, Dsc, Dc);

  // per-chunk M = (I+L)^{-1} (parallel; Gram + forward substitution)
  gram_inv<<<dim3(Bc * NCH), dim3(256), 0, stream>>>(feat, MTg);

  // chunked scan -> preds (512 blocks x 128 threads; 2 blocks/CU)
  ttt_scan<<<dim3(Bc * Dsc / 2), dim3(128), 0, stream>>>(feat, MTg, preds);

  // out = preds @ W_up + b_up + x   (M=8192, N=1024, K=256)
  gemm_bias<<<dim3(M / 64, Dc / 64), dim3(256), 0, stream>>>(
      preds, Wu, bu, x, out, M, Dc, Dsc);
}

// Round 14
// 312.005 us; speedup vs baseline: 1.0847x; 1.0847x over previous
//
#include <hip/hip_runtime.h>

#define LR 0.01f

// Problem constants (from reference setup_inputs): B=4, S=2048, D=1024, Ds=256
constexpr int Bc  = 4;
constexpr int Sc  = 2048;
constexpr int Dc  = 1024;
constexpr int Dsc = 256;

// ---------------------------------------------------------------------------
// Tiled fp32 GEMM (v10, verified): A-tile transposed in LDS, float4 reads,
// float4 epilogue.
// ---------------------------------------------------------------------------
__global__ __launch_bounds__(256) void gemm_bias(
    const float* __restrict__ A, const float* __restrict__ Bm,
    const float* __restrict__ bias, const float* __restrict__ resid,
    float* __restrict__ C, int M, int N, int K) {
  constexpr int BM = 64, BN = 64, BK = 16;
  __shared__ float As[BM][BK + 4];
  __shared__ float Bs[BK][BN + 4];

  const int bm = blockIdx.x * BM;
  const int bn = blockIdx.y * BN;
  const int tx = threadIdx.x & 15;
  const int ty = threadIdx.x >> 4;

  float acc[4][4] = {};

  for (int k0 = 0; k0 < K; k0 += BK) {
#pragma unroll
    for (int qq = 0; qq < 4; ++qq) {
      int m = ty + 16 * qq;
      As[m][tx] = A[(size_t)(bm + m) * K + k0 + tx];
    }
#pragma unroll
    for (int qq = 0; qq < 4; ++qq) {
      int i = threadIdx.x + 256 * qq;
      int k = i >> 6, n = i & 63;
      Bs[k][n] = Bm[(size_t)(k0 + k) * N + bn + n];
    }
    __syncthreads();
#pragma unroll
    for (int k4 = 0; k4 < BK; k4 += 4) {
      float4 a0 = *(const float4*)&As[ty * 4 + 0][k4];
      float4 a1 = *(const float4*)&As[ty * 4 + 1][k4];
      float4 a2 = *(const float4*)&As[ty * 4 + 2][k4];
      float4 a3 = *(const float4*)&As[ty * 4 + 3][k4];
      float4 b0 = *(const float4*)&Bs[k4 + 0][tx * 4];
      float4 b1 = *(const float4*)&Bs[k4 + 1][tx * 4];
      float4 b2 = *(const float4*)&Bs[k4 + 2][tx * 4];
      float4 b3 = *(const float4*)&Bs[k4 + 3][tx * 4];
#define ROWI(AI)                                          \
      acc[AI][0] = fmaf(a##AI.x, b0.x, acc[AI][0]);       \
      acc[AI][1] = fmaf(a##AI.x, b0.y, acc[AI][1]);       \
      acc[AI][2] = fmaf(a##AI.x, b0.z, acc[AI][2]);       \
      acc[AI][3] = fmaf(a##AI.x, b0.w, acc[AI][3]);       \
      acc[AI][0] = fmaf(a##AI.y, b1.x, acc[AI][0]);       \
      acc[AI][1] = fmaf(a##AI.y, b1.y, acc[AI][1]);       \
      acc[AI][2] = fmaf(a##AI.y, b1.z, acc[AI][2]);       \
      acc[AI][3] = fmaf(a##AI.y, b1.w, acc[AI][3]);       \
      acc[AI][0] = fmaf(a##AI.z, b2.x, acc[AI][0]);       \
      acc[AI][1] = fmaf(a##AI.z, b2.y, acc[AI][1]);       \
      acc[AI][2] = fmaf(a##AI.z, b2.z, acc[AI][2]);       \
      acc[AI][3] = fmaf(a##AI.z, b2.w, acc[AI][3]);       \
      acc[AI][0] = fmaf(a##AI.w, b3.x, acc[AI][0]);       \
      acc[AI][1] = fmaf(a##AI.w, b3.y, acc[AI][1]);       \
      acc[AI][2] = fmaf(a##AI.w, b3.z, acc[AI][2]);       \
      acc[AI][3] = fmaf(a##AI.w, b3.w, acc[AI][3]);
      ROWI(0) ROWI(1) ROWI(2) ROWI(3)
#undef ROWI
    }
    __syncthreads();
  }

  float4 bias4 = *(const float4*)&bias[bn + tx * 4];
#pragma unroll
  for (int i = 0; i < 4; ++i) {
    int m = bm + ty * 4 + i;
    float4 v;
    v.x = acc[i][0] + bias4.x;
    v.y = acc[i][1] + bias4.y;
    v.z = acc[i][2] + bias4.z;
    v.w = acc[i][3] + bias4.w;
    if (resid) {
      float4 r = *(const float4*)&resid[(size_t)m * N + bn + tx * 4];
      v.x += r.x; v.y += r.y; v.z += r.z; v.w += r.w;
    }
    *(float4*)&C[(size_t)m * N + bn + tx * 4] = v;
  }
}

// ---------------------------------------------------------------------------
// v15 scan: ROW-SPLIT chains -> 2048 waves = 2 waves/SIMD.
// v14 post-mortem: 512x2-wave kept total waves at 1024 = 1/SIMD (occupancy
// unchanged at 11.3%) -- stalls had no co-SIMD wave to hide behind. v15:
// block = 4 waves = 2 columns x 2 row-halves; 512 blocks; LDS 77KB -> 2
// blocks/CU -> 8 waves/CU = 2/SIMD. Per wave: 16-row P0 (reduces halved),
// MV over OWN-half s only (no d exchange needed!), e-partial exchange via
// LDS, ACCT over own rows, acc handoff rh1->rh0, w updated by rh0 only and
// published via LDS (single writer -> deterministic). Staging/handoff
// unchanged (per-wave 9 async ops, counted vmcnt(9)).
// ---------------------------------------------------------------------------

template <int CTRL, int RM>
__device__ __forceinline__ float dpp_sum(float v) {
  int moved = __builtin_amdgcn_update_dpp(0, __float_as_int(v), CTRL, RM, 0xF, false);
  return v + __int_as_float(moved);
}

__device__ __forceinline__ float rdlane(float v, int l) {
  return __int_as_float(__builtin_amdgcn_readlane(__float_as_int(v), l));
}

__device__ __forceinline__ void async_copy16(const float* g, float* l) {
  __builtin_amdgcn_global_load_lds(
      (const __attribute__((address_space(1))) unsigned int*)g,
      (__attribute__((address_space(3))) unsigned int*)l, 16, 0, 0);
}

constexpr int RCH = 32;        // rows per chunk
constexpr int NCH = Sc / RCH;  // 64 chunks

// MTg[bc][s*32+t] = M[t][s], M = (I + L)^{-1}, L[t][s] = LR*dot(f_t,f_s) s<t
__global__ __launch_bounds__(256) void gram_inv(const float* __restrict__ feat,
                                                float* __restrict__ MTg) {
  const int bc = blockIdx.x;  // 0..B*NCH-1
  __shared__ float Fl[32 * 260];
  __shared__ float Gl[32 * 32];
  __shared__ float Ml[32 * 32];
  const float* src = feat + (size_t)bc * RCH * Dsc;
  for (int i = threadIdx.x; i < 32 * 256; i += 256) {
    int r = i >> 8, cc = i & 255;
    Fl[r * 260 + cc] = src[i];
  }
  __syncthreads();
#pragma unroll
  for (int k2 = 0; k2 < 4; ++k2) {
    int idx = threadIdx.x + (k2 << 8);
    int t = idx >> 5, s = idx & 31;
    float sum = 0.f;
    if (s < t) {
      const float4* ft = (const float4*)&Fl[t * 260];
      const float4* fs = (const float4*)&Fl[s * 260];
#pragma unroll
      for (int i = 0; i < 64; ++i) {
        float4 a = ft[i], b = fs[i];
        sum = fmaf(a.x, b.x, sum); sum = fmaf(a.y, b.y, sum);
        sum = fmaf(a.z, b.z, sum); sum = fmaf(a.w, b.w, sum);
      }
      sum *= LR;
    }
    Gl[idx] = sum;  // L[t][s] (strict lower), 0 elsewhere
  }
  __syncthreads();
  // Forward substitution, column s per lane.
  if (threadIdx.x < 32) {
    const int s = threadIdx.x;
    for (int t = 0; t < 32; ++t) {
      float sum = 0.f;
      for (int u = 0; u < t; ++u)
        sum = fmaf(Gl[t * 32 + u], Ml[u * 32 + s], sum);
      Ml[t * 32 + s] = ((t == s) ? 1.f : 0.f) - sum;
    }
  }
  __syncthreads();
  float* dst = MTg + (size_t)bc * 1024;
#pragma unroll
  for (int k2 = 0; k2 < 4; ++k2) {
    int idx = threadIdx.x + (k2 << 8);
    int s = idx >> 5, t = idx & 31;
    dst[idx] = Ml[t * 32 + s];  // transposed store
  }
}

// Half-row X-macro lists (local row indices 0..15 within the wave's half).
#define HROWS_A(X) X(0) X(1) X(2) X(3) X(4) X(5) X(6) X(7)
#define HROWS_B(X) X(8) X(9) X(10) X(11) X(12) X(13) X(14) X(15)
#define HROWS_ALL(X) HROWS_A(X) HROWS_B(X)

__global__ __launch_bounds__(256) void ttt_scan(
    const float* __restrict__ feat, const float* __restrict__ MTg,
    float* __restrict__ preds) {
  const int lane = threadIdx.x & 63;
  const int wv   = threadIdx.x >> 6;   // 0..3
  const int lm   = lane & 31;
  const int cl   = wv & 1;             // column within block
  const int rh   = wv >> 1;            // row half (0: rows 0-15, 1: 16-31)
  const int rbase = rh << 4;

  // XCD-locality swizzle for 512 blocks (bijective).
  const int bi  = blockIdx.x;                    // 0..511
  const int xcd = bi & 7;
  const int b   = xcd >> 1;                      // 0..3
  const int q   = ((bi >> 3) << 1) | (xcd & 1);  // 0..127 col-pair within b
  const int j   = (q << 1) | cl;                 // 0..255

  __shared__ float  ldsF[2][RCH * Dsc];  // 64 KB
  __shared__ float  ldsM[2][1024];       // 8 KB
  __shared__ float  ldsE[2][2][64];      // 1 KB  e-partial exchange
  __shared__ float4 ldsA2[2][64];        // 2 KB  acc handoff (rh1 -> rh0)
  __shared__ float4 ldsW[2][64];         // 2 KB  w publish (rh0 -> rh1)
  // total 77 KB -> 2 blocks/CU (154 <= 160 KB)

  const float* fb0 = feat + (size_t)b * Sc * Dsc;
  const float* Mg  = MTg + (size_t)b * NCH * 1024;
  float* pb0 = preds + (size_t)b * Sc * Dsc + j;

// 9 async ops per wave per stage: 8 feat rows + 1 quarter of M.
#define STAGE(BUF, C0)                                                    \
  {                                                                       \
    _Pragma("unroll")                                                     \
    for (int r_ = 0; r_ < 8; ++r_) {                                      \
      const int row_ = (wv << 3) | r_;                                    \
      async_copy16(fb0 + (size_t)((C0) * RCH + row_) * Dsc + (lane << 2), \
                   &ldsF[BUF][row_ * Dsc]);                               \
    }                                                                     \
    async_copy16(Mg + (size_t)(C0) * 1024 + (wv << 8) + (lane << 2),      \
                 &ldsM[BUF][wv << 8]);                                    \
  }

#define DECLF(R) float4 F4_##R;
#define DECLD(R) float dsc_##R;

// One b128 per row (local R; global row = rbase+R via pF2).
#define LOADF(R) F4_##R = *(const float4*)&pF2[(R) * 256 + (lane << 2)];

// P0 for local row R: dot(f, w) -> DPP reduce -> uniform d = p0 - f[j].
#define P0C(R)                                                                 \
  {                                                                            \
    float dd = fmaf(F4_##R.y, w4y, F4_##R.x * w4x) +                           \
               fmaf(F4_##R.w, w4w, F4_##R.z * w4z);                            \
    dd = dpp_sum<0x111, 0xF>(dd);                                              \
    dd = dpp_sum<0x112, 0xF>(dd);                                              \
    dd = dpp_sum<0x114, 0xF>(dd);                                              \
    dd = dpp_sum<0x118, 0xF>(dd);                                              \
    dd = dpp_sum<0x142, 0xA>(dd);                                              \
    dd = dpp_sum<0x143, 0xC>(dd);                                              \
    float p0_ = rdlane(dd, 63);                                                \
    float fj_ = rdlane(v_fjcol, rbase + (R));                                  \
    dsc_##R = p0_ - fj_;                                                       \
  }

// Matvec, OWN-half s only: e_partial += M^T[rbase+S][lm] * d_{rbase+S}.
#define MV(S, EK) e##EK = fmaf(pM2[(S) * 32 + lm], dsc_##S, e##EK);

// acc += e_t * f_t over own rows (e_t from the full exchanged e).
#define ACCT(R)                                    \
  {                                                \
    float et_ = rdlane(v_e, rbase + (R));          \
    accx = fmaf(et_, F4_##R.x, accx);              \
    accy = fmaf(et_, F4_##R.y, accy);              \
    accz = fmaf(et_, F4_##R.z, accz);              \
    accw = fmaf(et_, F4_##R.w, accw);              \
  }

  // Prologue: stage chunks 0,1; wait chunk 0 (chunk 1's 9 may remain).
  STAGE(0, 0);
  STAGE(1, 1);
  asm volatile("s_waitcnt vmcnt(9)" ::: "memory");
  __builtin_amdgcn_s_barrier();
  __builtin_amdgcn_sched_barrier(0);

  float w4x = 0.f, w4y = 0.f, w4z = 0.f, w4w = 0.f;

#pragma unroll 1
  for (int c = 0; c < NCH; ++c) {
    const int cb = c & 1;
    const float* pF  = &ldsF[cb][0];
    const float* pF2 = pF + (rh << 12);          // + rh*16*256
    const float* pM2 = &ldsM[cb][rh << 9];       // + rh*16*32

    HROWS_ALL(DECLF)
    HROWS_ALL(DECLD)
    float e0 = 0.f, e1 = 0.f, e2 = 0.f, e3 = 0.f;
    float accx = 0.f, accy = 0.f, accz = 0.f, accw = 0.f;

    // FJ column (rows 0..31 in lanes 0..31; 32-way conflict, one instr).
    float v_fjcol = pF[lm * 256 + j];

    // Phase 1: own-half rows, loads one group ahead of reduces.
    HROWS_A(LOADF)
    HROWS_B(LOADF)
    __builtin_amdgcn_sched_barrier(0);
    HROWS_A(P0C)
    __builtin_amdgcn_sched_barrier(0);
    HROWS_B(P0C)

    // Phase 2: partial e over own-half s (no d exchange needed).
    MV(0, 0)  MV(1, 1)  MV(2, 2)  MV(3, 3)
    MV(4, 0)  MV(5, 1)  MV(6, 2)  MV(7, 3)
    MV(8, 0)  MV(9, 1)  MV(10, 2) MV(11, 3)
    MV(12, 0) MV(13, 1) MV(14, 2) MV(15, 3)
    float e_p = (e0 + e1) + (e2 + e3);

    // e exchange (both halves need full e).
    ldsE[cl][rh][lane] = e_p;
    __builtin_amdgcn_s_barrier();                 // bE
    float v_e = e_p + ldsE[cl][rh ^ 1][lane];

    // Phase 3: preds (single writer: rh==0).
    if (rh == 0 && lane < 32)
      pb0[(size_t)(c * RCH + lane) * Dsc] = v_e + v_fjcol;

    // Phase 4: partial acc over own rows.
    HROWS_ALL(ACCT)

    // acc handoff rh1 -> rh0; rh0 updates w and publishes it.
    if (rh == 1) ldsA2[cl][lane] = make_float4(accx, accy, accz, accw);
    __builtin_amdgcn_s_barrier();                 // bA
    if (rh == 0) {
      float4 o = ldsA2[cl][lane];
      accx += o.x; accy += o.y; accz += o.z; accw += o.w;
      w4x = fmaf(-LR, accx, w4x); w4y = fmaf(-LR, accy, w4y);
      w4z = fmaf(-LR, accz, w4z); w4w = fmaf(-LR, accw, w4w);
      ldsW[cl][lane] = make_float4(w4x, w4y, w4z, w4w);
    }
    __builtin_amdgcn_s_barrier();                 // pre-handoff (+ w publish)
    if (rh == 1) {
      float4 wvv = ldsW[cl][lane];
      w4x = wvv.x; w4y = wvv.y; w4z = wvv.z; w4w = wvv.w;
    }
    if (c + 2 < NCH) {
      STAGE(cb, c + 2);
      asm volatile("s_waitcnt vmcnt(9)" ::: "memory");
    } else {
      asm volatile("s_waitcnt vmcnt(0)" ::: "memory");
    }
    __builtin_amdgcn_s_barrier();                 // post-handoff
    __builtin_amdgcn_sched_barrier(0);
  }
#undef ACCT
#undef MV
#undef P0C
#undef LOADF
#undef DECLD
#undef DECLF
#undef STAGE
}

extern "C" void kernel_launch(void* const* d_in, const int* in_sizes, int n_in,
                              void* d_out, int out_size, void* d_ws, size_t ws_size,
                              hipStream_t stream) {
  const float* x  = (const float*)d_in[0];  // (B,S,D)
  const float* Wd = (const float*)d_in[1];  // (D,Ds)
  const float* bd = (const float*)d_in[2];  // (Ds)
  const float* Wu = (const float*)d_in[3];  // (Ds,D)
  const float* bu = (const float*)d_in[4];  // (D)
  float* out = (float*)d_out;               // (B,S,D)

  float* feat  = (float*)d_ws;                        // B*S*Ds f32 = 8 MB
  float* preds = feat + (size_t)Bc * Sc * Dsc;        // 8 MB
  float* MTg   = preds + (size_t)Bc * Sc * Dsc;       // B*NCH*1024 f32 = 1 MB

  const int M = Bc * Sc;  // 8192

  // feat = x @ W_down + b_down   (M=8192, N=256, K=1024)
  gemm_bias<<<dim3(M / 64, Dsc / 64), dim3(256), 0, stream>>>(
      x, Wd, bd, nullptr, feat, M, Dsc, Dc);

  // per-chunk M = (I+L)^{-1} (parallel; Gram + forward substitution)
  gram_inv<<<dim3(Bc * NCH), dim3(256), 0, stream>>>(feat, MTg);

  // chunked scan -> preds (512 blocks x 4 waves: 2 cols x 2 row-halves;
  // 2 blocks/CU -> 2 waves/SIMD)
  ttt_scan<<<dim3(Bc * Dsc / 2), dim3(256), 0, stream>>>(feat, MTg, preds);

  // out = preds @ W_up + b_up + x   (M=8192, N=1024, K=256)
  gemm_bias<<<dim3(M / 64, Dc / 64), dim3(256), 0, stream>>>(
      preds, Wu, bu, x, out, M, Dc, Dsc);
}

// Round 15
// 280.548 us; speedup vs baseline: 1.2063x; 1.1121x over previous
//
#include <hip/hip_runtime.h>

#define LR 0.01f

// Problem constants (from reference setup_inputs): B=4, S=2048, D=1024, Ds=256
constexpr int Bc  = 4;
constexpr int Sc  = 2048;
constexpr int Dc  = 1024;
constexpr int Dsc = 256;

// ---------------------------------------------------------------------------
// Tiled fp32 GEMM (v10, verified): A-tile transposed in LDS, float4 reads,
// float4 epilogue.
// ---------------------------------------------------------------------------
__global__ __launch_bounds__(256) void gemm_bias(
    const float* __restrict__ A, const float* __restrict__ Bm,
    const float* __restrict__ bias, const float* __restrict__ resid,
    float* __restrict__ C, int M, int N, int K) {
  constexpr int BM = 64, BN = 64, BK = 16;
  __shared__ float As[BM][BK + 4];
  __shared__ float Bs[BK][BN + 4];

  const int bm = blockIdx.x * BM;
  const int bn = blockIdx.y * BN;
  const int tx = threadIdx.x & 15;
  const int ty = threadIdx.x >> 4;

  float acc[4][4] = {};

  for (int k0 = 0; k0 < K; k0 += BK) {
#pragma unroll
    for (int qq = 0; qq < 4; ++qq) {
      int m = ty + 16 * qq;
      As[m][tx] = A[(size_t)(bm + m) * K + k0 + tx];
    }
#pragma unroll
    for (int qq = 0; qq < 4; ++qq) {
      int i = threadIdx.x + 256 * qq;
      int k = i >> 6, n = i & 63;
      Bs[k][n] = Bm[(size_t)(k0 + k) * N + bn + n];
    }
    __syncthreads();
#pragma unroll
    for (int k4 = 0; k4 < BK; k4 += 4) {
      float4 a0 = *(const float4*)&As[ty * 4 + 0][k4];
      float4 a1 = *(const float4*)&As[ty * 4 + 1][k4];
      float4 a2 = *(const float4*)&As[ty * 4 + 2][k4];
      float4 a3 = *(const float4*)&As[ty * 4 + 3][k4];
      float4 b0 = *(const float4*)&Bs[k4 + 0][tx * 4];
      float4 b1 = *(const float4*)&Bs[k4 + 1][tx * 4];
      float4 b2 = *(const float4*)&Bs[k4 + 2][tx * 4];
      float4 b3 = *(const float4*)&Bs[k4 + 3][tx * 4];
#define ROWI(AI)                                          \
      acc[AI][0] = fmaf(a##AI.x, b0.x, acc[AI][0]);       \
      acc[AI][1] = fmaf(a##AI.x, b0.y, acc[AI][1]);       \
      acc[AI][2] = fmaf(a##AI.x, b0.z, acc[AI][2]);       \
      acc[AI][3] = fmaf(a##AI.x, b0.w, acc[AI][3]);       \
      acc[AI][0] = fmaf(a##AI.y, b1.x, acc[AI][0]);       \
      acc[AI][1] = fmaf(a##AI.y, b1.y, acc[AI][1]);       \
      acc[AI][2] = fmaf(a##AI.y, b1.z, acc[AI][2]);       \
      acc[AI][3] = fmaf(a##AI.y, b1.w, acc[AI][3]);       \
      acc[AI][0] = fmaf(a##AI.z, b2.x, acc[AI][0]);       \
      acc[AI][1] = fmaf(a##AI.z, b2.y, acc[AI][1]);       \
      acc[AI][2] = fmaf(a##AI.z, b2.z, acc[AI][2]);       \
      acc[AI][3] = fmaf(a##AI.z, b2.w, acc[AI][3]);       \
      acc[AI][0] = fmaf(a##AI.w, b3.x, acc[AI][0]);       \
      acc[AI][1] = fmaf(a##AI.w, b3.y, acc[AI][1]);       \
      acc[AI][2] = fmaf(a##AI.w, b3.z, acc[AI][2]);       \
      acc[AI][3] = fmaf(a##AI.w, b3.w, acc[AI][3]);
      ROWI(0) ROWI(1) ROWI(2) ROWI(3)
#undef ROWI
    }
    __syncthreads();
  }

  float4 bias4 = *(const float4*)&bias[bn + tx * 4];
#pragma unroll
  for (int i = 0; i < 4; ++i) {
    int m = bm + ty * 4 + i;
    float4 v;
    v.x = acc[i][0] + bias4.x;
    v.y = acc[i][1] + bias4.y;
    v.z = acc[i][2] + bias4.z;
    v.w = acc[i][3] + bias4.w;
    if (resid) {
      float4 r = *(const float4*)&resid[(size_t)m * N + bn + tx * 4];
      v.x += r.x; v.y += r.y; v.z += r.z; v.w += r.w;
    }
    *(float4*)&C[(size_t)m * N + bn + tx * 4] = v;
  }
}

// ---------------------------------------------------------------------------
// v16 scan: quarter-split chains (4 waves/SIMD) + w' = w - e_j state trick
// + M in registers.
// v15 post-mortem: jointly LDS-pipe & issue bound at 2 waves/SIMD; FJ
// conflicts doubled (8.1M). Changes:
//  - state is w' = w - e_j (init -e_j; update identical since linear) ->
//    d_t = f_t . w' directly: no FJ read, no per-row readlane+sub. FJ read
//    (32-way conflict) only by the output wave (qr==0).
//  - M^T rows live in registers; chunk c+1's 8 values prefetched via plain
//    global loads (L2-resident). ldsM deleted. Counted wait = vmcnt(12)
//    (8 M loads + 4 stage ops in flight; in-order retirement).
//  - block = 512 threads = 2 cols x 4 row-quarters (8 rows/wave); 512
//    blocks; LDS 76KB -> 2 blocks/CU -> 16 waves/CU = 4/SIMD.
//  - quarter merge: e-partials via LDS (conflict-free), acc merged by qr==0
//    (single writer), w' published via LDS (deterministic across waves).
//  - 3 barriers/chunk (bE, bA, bFinal).
// ---------------------------------------------------------------------------

template <int CTRL, int RM>
__device__ __forceinline__ float dpp_sum(float v) {
  int moved = __builtin_amdgcn_update_dpp(0, __float_as_int(v), CTRL, RM, 0xF, false);
  return v + __int_as_float(moved);
}

__device__ __forceinline__ float rdlane(float v, int l) {
  return __int_as_float(__builtin_amdgcn_readlane(__float_as_int(v), l));
}

__device__ __forceinline__ void async_copy16(const float* g, float* l) {
  __builtin_amdgcn_global_load_lds(
      (const __attribute__((address_space(1))) unsigned int*)g,
      (__attribute__((address_space(3))) unsigned int*)l, 16, 0, 0);
}

constexpr int RCH = 32;        // rows per chunk
constexpr int NCH = Sc / RCH;  // 64 chunks

// MTg[bc][s*32+t] = M[t][s], M = (I + L)^{-1}, L[t][s] = LR*dot(f_t,f_s) s<t
__global__ __launch_bounds__(256) void gram_inv(const float* __restrict__ feat,
                                                float* __restrict__ MTg) {
  const int bc = blockIdx.x;  // 0..B*NCH-1
  __shared__ float Fl[32 * 260];
  __shared__ float Gl[32 * 32];
  __shared__ float Ml[32 * 32];
  const float* src = feat + (size_t)bc * RCH * Dsc;
  for (int i = threadIdx.x; i < 32 * 256; i += 256) {
    int r = i >> 8, cc = i & 255;
    Fl[r * 260 + cc] = src[i];
  }
  __syncthreads();
#pragma unroll
  for (int k2 = 0; k2 < 4; ++k2) {
    int idx = threadIdx.x + (k2 << 8);
    int t = idx >> 5, s = idx & 31;
    float sum = 0.f;
    if (s < t) {
      const float4* ft = (const float4*)&Fl[t * 260];
      const float4* fs = (const float4*)&Fl[s * 260];
#pragma unroll
      for (int i = 0; i < 64; ++i) {
        float4 a = ft[i], b = fs[i];
        sum = fmaf(a.x, b.x, sum); sum = fmaf(a.y, b.y, sum);
        sum = fmaf(a.z, b.z, sum); sum = fmaf(a.w, b.w, sum);
      }
      sum *= LR;
    }
    Gl[idx] = sum;
  }
  __syncthreads();
  if (threadIdx.x < 32) {
    const int s = threadIdx.x;
    for (int t = 0; t < 32; ++t) {
      float sum = 0.f;
      for (int u = 0; u < t; ++u)
        sum = fmaf(Gl[t * 32 + u], Ml[u * 32 + s], sum);
      Ml[t * 32 + s] = ((t == s) ? 1.f : 0.f) - sum;
    }
  }
  __syncthreads();
  float* dst = MTg + (size_t)bc * 1024;
#pragma unroll
  for (int k2 = 0; k2 < 4; ++k2) {
    int idx = threadIdx.x + (k2 << 8);
    int s = idx >> 5, t = idx & 31;
    dst[idx] = Ml[t * 32 + s];  // transposed store
  }
}

// Per-wave local rows 0..7.
#define QROWS(X) X(0) X(1) X(2) X(3) X(4) X(5) X(6) X(7)

__global__ __launch_bounds__(512, 4) void ttt_scan(
    const float* __restrict__ feat, const float* __restrict__ MTg,
    float* __restrict__ preds) {
  const int lane = threadIdx.x & 63;
  const int wv   = threadIdx.x >> 6;   // 0..7
  const int lm   = lane & 31;
  const int cl   = wv & 1;             // column within block
  const int qr   = wv >> 1;            // row quarter (8 rows each)
  const int rbase = qr << 3;

  // XCD-locality swizzle for 512 blocks (bijective).
  const int bi  = blockIdx.x;                    // 0..511
  const int xcd = bi & 7;
  const int b   = xcd >> 1;                      // 0..3
  const int q   = ((bi >> 3) << 1) | (xcd & 1);  // 0..127 col-pair within b
  const int j   = (q << 1) | cl;                 // 0..255

  __shared__ float  ldsF[2][RCH * Dsc];  // 64 KB
  __shared__ float  ldsE[2][4][64];      // 2 KB  e-partial exchange
  __shared__ float4 ldsA[2][4][64];      // 8 KB  acc partials (qr 1..3 used)
  __shared__ float4 ldsW[2][64];         // 2 KB  w' publish (qr0 -> others)
  // total 76 KB -> 2 blocks/CU (152 <= 160 KB) = 16 waves/CU = 4/SIMD

  const float* fb0 = feat + (size_t)b * Sc * Dsc;
  const float* Mg  = MTg + (size_t)b * NCH * 1024;
  float* pb0 = preds + (size_t)b * Sc * Dsc + j;

// 4 async ops per wave per stage (32 rows / 8 waves).
#define STAGE(BUF, C0)                                                    \
  {                                                                       \
    _Pragma("unroll")                                                     \
    for (int r_ = 0; r_ < 4; ++r_) {                                      \
      const int row_ = (wv << 2) | r_;                                    \
      async_copy16(fb0 + (size_t)((C0) * RCH + row_) * Dsc + (lane << 2), \
                   &ldsF[BUF][row_ * Dsc]);                               \
    }                                                                     \
  }

// M prefetch for chunk C1 into Mn regs (8 plain global loads, L2-resident).
#define LOADM(C1)                                          \
  {                                                        \
    const float* mp_ = Mg + (size_t)(C1) * 1024 + lm;      \
    Mn0 = mp_[(rbase + 0) * 32]; Mn1 = mp_[(rbase + 1) * 32]; \
    Mn2 = mp_[(rbase + 2) * 32]; Mn3 = mp_[(rbase + 3) * 32]; \
    Mn4 = mp_[(rbase + 4) * 32]; Mn5 = mp_[(rbase + 5) * 32]; \
    Mn6 = mp_[(rbase + 6) * 32]; Mn7 = mp_[(rbase + 7) * 32]; \
  }

#define DECLF(R) float4 F4_##R;
#define DECLD(R) float dsc_##R;

// One b128 per local row (global row = rbase+R via pF2).
#define LOADF(R) F4_##R = *(const float4*)&pF2[(R) * 256 + (lane << 2)];

// P0 with w' state: d = f . w' directly (no FJ, no subtract).
#define P0C(R)                                                                 \
  {                                                                            \
    float dd = fmaf(F4_##R.y, w4y, F4_##R.x * w4x) +                           \
               fmaf(F4_##R.w, w4w, F4_##R.z * w4z);                            \
    dd = dpp_sum<0x111, 0xF>(dd);                                              \
    dd = dpp_sum<0x112, 0xF>(dd);                                              \
    dd = dpp_sum<0x114, 0xF>(dd);                                              \
    dd = dpp_sum<0x118, 0xF>(dd);                                              \
    dd = dpp_sum<0x142, 0xA>(dd);                                              \
    dd = dpp_sum<0x143, 0xC>(dd);                                              \
    dsc_##R = rdlane(dd, 63);                                                  \
  }

// Matvec over OWN-quarter s (M in registers, d uniform).
#define MV(R) e_p = fmaf(Mc##R, dsc_##R, e_p);

// acc += e_t * f_t over own rows.
#define ACCT(R)                                    \
  {                                                \
    float et_ = rdlane(v_e, rbase + (R));          \
    accx = fmaf(et_, F4_##R.x, accx);              \
    accy = fmaf(et_, F4_##R.y, accy);              \
    accz = fmaf(et_, F4_##R.z, accz);              \
    accw = fmaf(et_, F4_##R.w, accw);              \
  }

  float Mc0, Mc1, Mc2, Mc3, Mc4, Mc5, Mc6, Mc7;
  float Mn0, Mn1, Mn2, Mn3, Mn4, Mn5, Mn6, Mn7;

  // Prologue: stage chunks 0,1 (8 ops) + M for chunk 0 (8 loads).
  STAGE(0, 0);
  STAGE(1, 1);
  LOADM(0);
  Mc0 = Mn0; Mc1 = Mn1; Mc2 = Mn2; Mc3 = Mn3;
  Mc4 = Mn4; Mc5 = Mn5; Mc6 = Mn6; Mc7 = Mn7;
  asm volatile("s_waitcnt vmcnt(12)" ::: "memory");  // stage-0 (oldest 4) done
  __builtin_amdgcn_s_barrier();
  __builtin_amdgcn_sched_barrier(0);

  // w' = w - e_j state: init -e_j (component j&3 of lane j>>2).
  const int jl4 = j >> 2, jc = j & 3;
  float w4x = (lane == jl4 && jc == 0) ? -1.f : 0.f;
  float w4y = (lane == jl4 && jc == 1) ? -1.f : 0.f;
  float w4z = (lane == jl4 && jc == 2) ? -1.f : 0.f;
  float w4w = (lane == jl4 && jc == 3) ? -1.f : 0.f;

#pragma unroll 1
  for (int c = 0; c < NCH; ++c) {
    const int cb = c & 1;
    const float* pF  = &ldsF[cb][0];
    const float* pF2 = pF + (rbase << 8);   // + rbase*256

    // M prefetch for next chunk (latency spans the whole chunk).
    if (c + 1 < NCH) LOADM(c + 1);

    QROWS(DECLF)
    QROWS(DECLD)
    float e_p = 0.f;
    float accx = 0.f, accy = 0.f, accz = 0.f, accw = 0.f;

    // FJ column only in the output wave (32-way conflict, 1 instr).
    float v_fjcol = 0.f;
    if (qr == 0) v_fjcol = pF[lm * 256 + j];

    // Phase 1: 8 own rows; loads grouped ahead of reduces.
    QROWS(LOADF)
    __builtin_amdgcn_sched_barrier(0);
    QROWS(P0C)

    // Phase 2: partial e over own-quarter s (registers only).
    MV(0) MV(1) MV(2) MV(3) MV(4) MV(5) MV(6) MV(7)

    // e exchange across quarters (fixed order -> deterministic).
    ldsE[cl][qr][lane] = e_p;
    __builtin_amdgcn_s_barrier();                 // bE
    float v_e = (ldsE[cl][0][lane] + ldsE[cl][1][lane]) +
                (ldsE[cl][2][lane] + ldsE[cl][3][lane]);

    // Phase 3: preds (single writer: qr==0).
    if (qr == 0 && lane < 32)
      pb0[(size_t)(c * RCH + lane) * Dsc] = v_e + v_fjcol;

    // Phase 4: partial acc over own rows.
    QROWS(ACCT)

    // acc merge by qr0 (single writer -> deterministic w').
    if (qr != 0) ldsA[cl][qr][lane] = make_float4(accx, accy, accz, accw);
    __builtin_amdgcn_s_barrier();                 // bA
    if (qr == 0) {
      float4 a1 = ldsA[cl][1][lane], a2 = ldsA[cl][2][lane],
             a3 = ldsA[cl][3][lane];
      accx += a1.x + a2.x + a3.x; accy += a1.y + a2.y + a3.y;
      accz += a1.z + a2.z + a3.z; accw += a1.w + a2.w + a3.w;
      w4x = fmaf(-LR, accx, w4x); w4y = fmaf(-LR, accy, w4y);
      w4z = fmaf(-LR, accz, w4z); w4w = fmaf(-LR, accw, w4w);
      ldsW[cl][lane] = make_float4(w4x, w4y, w4z, w4w);
    }

    // Handoff: stage c+2 over cb (reads of cb all finished before bE<bA);
    // counted vmcnt(12) = 8 Mn + 4 stage-c+2 in flight -> stage-c+1 done.
    if (c + 2 < NCH) {
      STAGE(cb, c + 2);
      asm volatile("s_waitcnt vmcnt(12)" ::: "memory");
    } else {
      asm volatile("s_waitcnt vmcnt(0)" ::: "memory");
    }
    __builtin_amdgcn_s_barrier();                 // bFinal (w' + stage vis)
    if (qr != 0) {
      float4 wp = ldsW[cl][lane];
      w4x = wp.x; w4y = wp.y; w4z = wp.z; w4w = wp.w;
    }
    Mc0 = Mn0; Mc1 = Mn1; Mc2 = Mn2; Mc3 = Mn3;
    Mc4 = Mn4; Mc5 = Mn5; Mc6 = Mn6; Mc7 = Mn7;
    __builtin_amdgcn_sched_barrier(0);
  }
#undef ACCT
#undef MV
#undef P0C
#undef LOADF
#undef DECLD
#undef DECLF
#undef LOADM
#undef STAGE
}

extern "C" void kernel_launch(void* const* d_in, const int* in_sizes, int n_in,
                              void* d_out, int out_size, void* d_ws, size_t ws_size,
                              hipStream_t stream) {
  const float* x  = (const float*)d_in[0];  // (B,S,D)
  const float* Wd = (const float*)d_in[1];  // (D,Ds)
  const float* bd = (const float*)d_in[2];  // (Ds)
  const float* Wu = (const float*)d_in[3];  // (Ds,D)
  const float* bu = (const float*)d_in[4];  // (D)
  float* out = (float*)d_out;               // (B,S,D)

  float* feat  = (float*)d_ws;                        // B*S*Ds f32 = 8 MB
  float* preds = feat + (size_t)Bc * Sc * Dsc;        // 8 MB
  float* MTg   = preds + (size_t)Bc * Sc * Dsc;       // B*NCH*1024 f32 = 1 MB

  const int M = Bc * Sc;  // 8192

  // feat = x @ W_down + b_down   (M=8192, N=256, K=1024)
  gemm_bias<<<dim3(M / 64, Dsc / 64), dim3(256), 0, stream>>>(
      x, Wd, bd, nullptr, feat, M, Dsc, Dc);

  // per-chunk M = (I+L)^{-1} (parallel; Gram + forward substitution)
  gram_inv<<<dim3(Bc * NCH), dim3(256), 0, stream>>>(feat, MTg);

  // chunked scan -> preds (512 blocks x 8 waves: 2 cols x 4 quarters;
  // 2 blocks/CU -> 4 waves/SIMD)
  ttt_scan<<<dim3(Bc * Dsc / 2), dim3(512), 0, stream>>>(feat, MTg, preds);

  // out = preds @ W_up + b_up + x   (M=8192, N=1024, K=256)
  gemm_bias<<<dim3(M / 64, Dc / 64), dim3(256), 0, stream>>>(
      preds, Wu, bu, x, out, M, Dc, Dsc);
}

// Round 17
// 249.687 us; speedup vs baseline: 1.3554x; 1.1236x over previous
//
#include <hip/hip_runtime.h>

#define LR 0.01f

// Problem constants (from reference setup_inputs): B=4, S=2048, D=1024, Ds=256
constexpr int Bc  = 4;
constexpr int Sc  = 2048;
constexpr int Dc  = 1024;
constexpr int Dsc = 256;

typedef unsigned short u16;
typedef __attribute__((ext_vector_type(8))) short bf16x8;
typedef __attribute__((ext_vector_type(4))) float f32x4;

__device__ __forceinline__ u16 f2bf(float f) {
  unsigned u = __float_as_uint(f);
  unsigned r = (u + 0x7fff + ((u >> 16) & 1)) >> 16;  // round-to-nearest-even
  return (u16)r;
}
__device__ __forceinline__ float bf2f(u16 h) {
  return __uint_as_float((unsigned)h << 16);
}

__device__ __forceinline__ void async_cp16(const void* g, void* l) {
  __builtin_amdgcn_global_load_lds(
      (const __attribute__((address_space(1))) unsigned int*)g,
      (__attribute__((address_space(3))) unsigned int*)l, 16, 0, 0);
}

// ---------------------------------------------------------------------------
// v18: GEMM1 back to fp32 (feat bit-exact -> no recurrence-amplified error);
// GEMM2 = bf16 MFMA with HI/LO-split A operand (preds represented to ~2^-16
// rel; only Wu quantization remains, non-compounding). v17 failed at 89.0 vs
// 84.5 threshold from the two bf16 error paths combined.
// ---------------------------------------------------------------------------

// ---------------------------------------------------------------------------
// Tiled fp32 GEMM (v10, verified): A-tile transposed in LDS, float4 reads,
// float4 epilogue.
// ---------------------------------------------------------------------------
__global__ __launch_bounds__(256) void gemm_bias(
    const float* __restrict__ A, const float* __restrict__ Bm,
    const float* __restrict__ bias, const float* __restrict__ resid,
    float* __restrict__ C, int M, int N, int K) {
  constexpr int BM = 64, BN = 64, BK = 16;
  __shared__ float As[BM][BK + 4];
  __shared__ float Bs[BK][BN + 4];

  const int bm = blockIdx.x * BM;
  const int bn = blockIdx.y * BN;
  const int tx = threadIdx.x & 15;
  const int ty = threadIdx.x >> 4;

  float acc[4][4] = {};

  for (int k0 = 0; k0 < K; k0 += BK) {
#pragma unroll
    for (int qq = 0; qq < 4; ++qq) {
      int m = ty + 16 * qq;
      As[m][tx] = A[(size_t)(bm + m) * K + k0 + tx];
    }
#pragma unroll
    for (int qq = 0; qq < 4; ++qq) {
      int i = threadIdx.x + 256 * qq;
      int k = i >> 6, n = i & 63;
      Bs[k][n] = Bm[(size_t)(k0 + k) * N + bn + n];
    }
    __syncthreads();
#pragma unroll
    for (int k4 = 0; k4 < BK; k4 += 4) {
      float4 a0 = *(const float4*)&As[ty * 4 + 0][k4];
      float4 a1 = *(const float4*)&As[ty * 4 + 1][k4];
      float4 a2 = *(const float4*)&As[ty * 4 + 2][k4];
      float4 a3 = *(const float4*)&As[ty * 4 + 3][k4];
      float4 b0 = *(const float4*)&Bs[k4 + 0][tx * 4];
      float4 b1 = *(const float4*)&Bs[k4 + 1][tx * 4];
      float4 b2 = *(const float4*)&Bs[k4 + 2][tx * 4];
      float4 b3 = *(const float4*)&Bs[k4 + 3][tx * 4];
#define ROWI(AI)                                          \
      acc[AI][0] = fmaf(a##AI.x, b0.x, acc[AI][0]);       \
      acc[AI][1] = fmaf(a##AI.x, b0.y, acc[AI][1]);       \
      acc[AI][2] = fmaf(a##AI.x, b0.z, acc[AI][2]);       \
      acc[AI][3] = fmaf(a##AI.x, b0.w, acc[AI][3]);       \
      acc[AI][0] = fmaf(a##AI.y, b1.x, acc[AI][0]);       \
      acc[AI][1] = fmaf(a##AI.y, b1.y, acc[AI][1]);       \
      acc[AI][2] = fmaf(a##AI.y, b1.z, acc[AI][2]);       \
      acc[AI][3] = fmaf(a##AI.y, b1.w, acc[AI][3]);       \
      acc[AI][0] = fmaf(a##AI.z, b2.x, acc[AI][0]);       \
      acc[AI][1] = fmaf(a##AI.z, b2.y, acc[AI][1]);       \
      acc[AI][2] = fmaf(a##AI.z, b2.z, acc[AI][2]);       \
      acc[AI][3] = fmaf(a##AI.z, b2.w, acc[AI][3]);       \
      acc[AI][0] = fmaf(a##AI.w, b3.x, acc[AI][0]);       \
      acc[AI][1] = fmaf(a##AI.w, b3.y, acc[AI][1]);       \
      acc[AI][2] = fmaf(a##AI.w, b3.z, acc[AI][2]);       \
      acc[AI][3] = fmaf(a##AI.w, b3.w, acc[AI][3]);
      ROWI(0) ROWI(1) ROWI(2) ROWI(3)
#undef ROWI
    }
    __syncthreads();
  }

  float4 bias4 = *(const float4*)&bias[bn + tx * 4];
#pragma unroll
  for (int i = 0; i < 4; ++i) {
    int m = bm + ty * 4 + i;
    float4 v;
    v.x = acc[i][0] + bias4.x;
    v.y = acc[i][1] + bias4.y;
    v.z = acc[i][2] + bias4.z;
    v.w = acc[i][3] + bias4.w;
    if (resid) {
      float4 r = *(const float4*)&resid[(size_t)m * N + bn + tx * 4];
      v.x += r.x; v.y += r.y; v.z += r.z; v.w += r.w;
    }
    *(float4*)&C[(size_t)m * N + bn + tx * 4] = v;
  }
}

// W [K][N] fp32 -> WT [N][K] bf16 (tiled LDS transpose).
__global__ __launch_bounds__(256) void castT_bf16(const float* __restrict__ W,
                                                  u16* __restrict__ WT,
                                                  int K, int N) {
  __shared__ float t[32][33];
  const int bk = blockIdx.x * 32, bn = blockIdx.y * 32;
  const int tx = threadIdx.x & 31, ty = threadIdx.x >> 5;  // 8 rows/pass
  for (int r = ty; r < 32; r += 8) t[r][tx] = W[(size_t)(bk + r) * N + bn + tx];
  __syncthreads();
  for (int r = ty; r < 32; r += 8)
    WT[(size_t)(bn + r) * K + bk + tx] = f2bf(t[tx][r]);
}

// ---------------------------------------------------------------------------
// bf16 MFMA GEMM with HI/LO-split A: C = (Ahi+Alo) @ B + bias (+resid).
// A split bf16 [M][K] x2; B TRANSPOSED bf16 [N][K]. 64x64 tile, BK=32,
// 4 waves each owning a 32x32 quadrant = 2x2x2 mfma_f32_16x16x32_bf16 per
// K-step. Frag maps verified functionally in v17 (absmax was quantization-
// level, not structural). Double-buffered LDS, counted vmcnt(3) handoff.
// ---------------------------------------------------------------------------
__global__ __launch_bounds__(256) void gemm_bf16_split(
    const u16* __restrict__ Ahi, const u16* __restrict__ Alo,
    const u16* __restrict__ BT, const float* __restrict__ bias,
    const float* __restrict__ resid, float* __restrict__ C,
    int M, int N, int K) {
  constexpr int BM = 64, BN = 64, BK = 32;
  __shared__ u16 sAh[2][BM * BK];
  __shared__ u16 sAl[2][BM * BK];
  __shared__ u16 sB[2][BN * BK];

  const int wv = threadIdx.x >> 6, lane = threadIdx.x & 63;
  const int bm = blockIdx.x * BM, bn = blockIdx.y * BN;
  const int qm = (wv >> 1) * 32, qn = (wv & 1) * 32;
  const int lr = lane & 15, lk = lane >> 4;

  const int srow = lane >> 2;        // staging row within the wave's 16
  const int skp  = (lane & 3) * 8;   // staging k-offset (elements)
  const int NKS = K / BK;

// Each wave: 3 async ops (Ahi rows, Alo rows, BT rows). Dest is wave-uniform
// base + lane*16B = linear [64][32] bf16 tile.
#define GSTAGE(BUF, KS)                                                   \
  {                                                                       \
    async_cp16(Ahi + (size_t)(bm + wv * 16 + srow) * K + (KS)*BK + skp,   \
               &sAh[BUF][wv * 512]);                                      \
    async_cp16(Alo + (size_t)(bm + wv * 16 + srow) * K + (KS)*BK + skp,   \
               &sAl[BUF][wv * 512]);                                      \
    async_cp16(BT + (size_t)(bn + wv * 16 + srow) * K + (KS)*BK + skp,    \
               &sB[BUF][wv * 512]);                                       \
  }

  f32x4 acc00 = {0.f, 0.f, 0.f, 0.f}, acc01 = {0.f, 0.f, 0.f, 0.f};
  f32x4 acc10 = {0.f, 0.f, 0.f, 0.f}, acc11 = {0.f, 0.f, 0.f, 0.f};

  GSTAGE(0, 0);
  GSTAGE(1, 1);
  asm volatile("s_waitcnt vmcnt(3)" ::: "memory");  // stage-0's 3 ops done
  __builtin_amdgcn_s_barrier();

  for (int ks = 0; ks < NKS; ++ks) {
    const int cb = ks & 1;
    const u16* pAh = &sAh[cb][0];
    const u16* pAl = &sAl[cb][0];
    const u16* pB  = &sB[cb][0];
    bf16x8 ah0 = *(const bf16x8*)&pAh[(qm + lr) * BK + lk * 8];
    bf16x8 ah1 = *(const bf16x8*)&pAh[(qm + 16 + lr) * BK + lk * 8];
    bf16x8 al0 = *(const bf16x8*)&pAl[(qm + lr) * BK + lk * 8];
    bf16x8 al1 = *(const bf16x8*)&pAl[(qm + 16 + lr) * BK + lk * 8];
    bf16x8 b0  = *(const bf16x8*)&pB[(qn + lr) * BK + lk * 8];
    bf16x8 b1  = *(const bf16x8*)&pB[(qn + 16 + lr) * BK + lk * 8];
    acc00 = __builtin_amdgcn_mfma_f32_16x16x32_bf16(ah0, b0, acc00, 0, 0, 0);
    acc01 = __builtin_amdgcn_mfma_f32_16x16x32_bf16(ah0, b1, acc01, 0, 0, 0);
    acc10 = __builtin_amdgcn_mfma_f32_16x16x32_bf16(ah1, b0, acc10, 0, 0, 0);
    acc11 = __builtin_amdgcn_mfma_f32_16x16x32_bf16(ah1, b1, acc11, 0, 0, 0);
    acc00 = __builtin_amdgcn_mfma_f32_16x16x32_bf16(al0, b0, acc00, 0, 0, 0);
    acc01 = __builtin_amdgcn_mfma_f32_16x16x32_bf16(al0, b1, acc01, 0, 0, 0);
    acc10 = __builtin_amdgcn_mfma_f32_16x16x32_bf16(al1, b0, acc10, 0, 0, 0);
    acc11 = __builtin_amdgcn_mfma_f32_16x16x32_bf16(al1, b1, acc11, 0, 0, 0);
    __builtin_amdgcn_s_barrier();  // all waves done reading buf cb
    if (ks + 2 < NKS) {
      GSTAGE(cb, ks + 2);
      asm volatile("s_waitcnt vmcnt(3)" ::: "memory");  // stage ks+1 done
    } else {
      asm volatile("s_waitcnt vmcnt(0)" ::: "memory");
    }
    __builtin_amdgcn_s_barrier();
  }

#define WRT(ACC, AR, BC)                                                 \
  {                                                                      \
    _Pragma("unroll")                                                    \
    for (int r = 0; r < 4; ++r) {                                        \
      int row = bm + qm + (AR) + lk * 4 + r;                             \
      int col = bn + qn + (BC) + lr;                                     \
      float v = ACC[r] + bias[col];                                      \
      if (resid) v += resid[(size_t)row * N + col];                      \
      C[(size_t)row * N + col] = v;                                      \
    }                                                                    \
  }
  WRT(acc00, 0, 0) WRT(acc01, 0, 16) WRT(acc10, 16, 0) WRT(acc11, 16, 16)
#undef WRT
#undef GSTAGE
}

// ---------------------------------------------------------------------------
// Scan machinery (v16, verified @ 150us): unchanged except preds stored as
// hi/lo bf16 pair.
// ---------------------------------------------------------------------------

template <int CTRL, int RM>
__device__ __forceinline__ float dpp_sum(float v) {
  int moved = __builtin_amdgcn_update_dpp(0, __float_as_int(v), CTRL, RM, 0xF, false);
  return v + __int_as_float(moved);
}

__device__ __forceinline__ float rdlane(float v, int l) {
  return __int_as_float(__builtin_amdgcn_readlane(__float_as_int(v), l));
}

constexpr int RCH = 32;        // rows per chunk
constexpr int NCH = Sc / RCH;  // 64 chunks

// MTg[bc][s*32+t] = M[t][s], M = (I + L)^{-1}, L[t][s] = LR*dot(f_t,f_s) s<t
__global__ __launch_bounds__(256) void gram_inv(const float* __restrict__ feat,
                                                float* __restrict__ MTg) {
  const int bc = blockIdx.x;  // 0..B*NCH-1
  __shared__ float Fl[32 * 260];
  __shared__ float Gl[32 * 32];
  __shared__ float Ml[32 * 32];
  const float* src = feat + (size_t)bc * RCH * Dsc;
  for (int i = threadIdx.x; i < 32 * 256; i += 256) {
    int r = i >> 8, cc = i & 255;
    Fl[r * 260 + cc] = src[i];
  }
  __syncthreads();
#pragma unroll
  for (int k2 = 0; k2 < 4; ++k2) {
    int idx = threadIdx.x + (k2 << 8);
    int t = idx >> 5, s = idx & 31;
    float sum = 0.f;
    if (s < t) {
      const float4* ft = (const float4*)&Fl[t * 260];
      const float4* fs = (const float4*)&Fl[s * 260];
#pragma unroll
      for (int i = 0; i < 64; ++i) {
        float4 a = ft[i], b = fs[i];
        sum = fmaf(a.x, b.x, sum); sum = fmaf(a.y, b.y, sum);
        sum = fmaf(a.z, b.z, sum); sum = fmaf(a.w, b.w, sum);
      }
      sum *= LR;
    }
    Gl[idx] = sum;
  }
  __syncthreads();
  if (threadIdx.x < 32) {
    const int s = threadIdx.x;
    for (int t = 0; t < 32; ++t) {
      float sum = 0.f;
      for (int u = 0; u < t; ++u)
        sum = fmaf(Gl[t * 32 + u], Ml[u * 32 + s], sum);
      Ml[t * 32 + s] = ((t == s) ? 1.f : 0.f) - sum;
    }
  }
  __syncthreads();
  float* dst = MTg + (size_t)bc * 1024;
#pragma unroll
  for (int k2 = 0; k2 < 4; ++k2) {
    int idx = threadIdx.x + (k2 << 8);
    int s = idx >> 5, t = idx & 31;
    dst[idx] = Ml[t * 32 + s];  // transposed store
  }
}

__device__ __forceinline__ void async_copy16f(const float* g, float* l) {
  __builtin_amdgcn_global_load_lds(
      (const __attribute__((address_space(1))) unsigned int*)g,
      (__attribute__((address_space(3))) unsigned int*)l, 16, 0, 0);
}

// Per-wave local rows 0..7.
#define QROWS(X) X(0) X(1) X(2) X(3) X(4) X(5) X(6) X(7)

__global__ __launch_bounds__(512, 4) void ttt_scan(
    const float* __restrict__ feat, const float* __restrict__ MTg,
    u16* __restrict__ predsHi, u16* __restrict__ predsLo) {
  const int lane = threadIdx.x & 63;
  const int wv   = threadIdx.x >> 6;   // 0..7
  const int lm   = lane & 31;
  const int cl   = wv & 1;             // column within block
  const int qr   = wv >> 1;            // row quarter (8 rows each)
  const int rbase = qr << 3;

  // XCD-locality swizzle for 512 blocks (bijective).
  const int bi  = blockIdx.x;                    // 0..511
  const int xcd = bi & 7;
  const int b   = xcd >> 1;                      // 0..3
  const int q   = ((bi >> 3) << 1) | (xcd & 1);  // 0..127 col-pair within b
  const int j   = (q << 1) | cl;                 // 0..255

  __shared__ float  ldsF[2][RCH * Dsc];  // 64 KB
  __shared__ float  ldsE[2][4][64];      // 2 KB  e-partial exchange
  __shared__ float4 ldsA[2][4][64];      // 8 KB  acc partials (qr 1..3 used)
  __shared__ float4 ldsW[2][64];         // 2 KB  w' publish (qr0 -> others)

  const float* fb0 = feat + (size_t)b * Sc * Dsc;
  const float* Mg  = MTg + (size_t)b * NCH * 1024;
  u16* pbh = predsHi + (size_t)b * Sc * Dsc + j;
  u16* pbl = predsLo + (size_t)b * Sc * Dsc + j;

#define STAGE(BUF, C0)                                                     \
  {                                                                        \
    _Pragma("unroll")                                                      \
    for (int r_ = 0; r_ < 4; ++r_) {                                       \
      const int row_ = (wv << 2) | r_;                                     \
      async_copy16f(fb0 + (size_t)((C0) * RCH + row_) * Dsc + (lane << 2), \
                    &ldsF[BUF][row_ * Dsc]);                               \
    }                                                                      \
  }

#define LOADM(C1)                                          \
  {                                                        \
    const float* mp_ = Mg + (size_t)(C1) * 1024 + lm;      \
    Mn0 = mp_[(rbase + 0) * 32]; Mn1 = mp_[(rbase + 1) * 32]; \
    Mn2 = mp_[(rbase + 2) * 32]; Mn3 = mp_[(rbase + 3) * 32]; \
    Mn4 = mp_[(rbase + 4) * 32]; Mn5 = mp_[(rbase + 5) * 32]; \
    Mn6 = mp_[(rbase + 6) * 32]; Mn7 = mp_[(rbase + 7) * 32]; \
  }

#define DECLF(R) float4 F4_##R;
#define DECLD(R) float dsc_##R;

#define LOADF(R) F4_##R = *(const float4*)&pF2[(R) * 256 + (lane << 2)];

#define P0C(R)                                                                 \
  {                                                                            \
    float dd = fmaf(F4_##R.y, w4y, F4_##R.x * w4x) +                           \
               fmaf(F4_##R.w, w4w, F4_##R.z * w4z);                            \
    dd = dpp_sum<0x111, 0xF>(dd);                                              \
    dd = dpp_sum<0x112, 0xF>(dd);                                              \
    dd = dpp_sum<0x114, 0xF>(dd);                                              \
    dd = dpp_sum<0x118, 0xF>(dd);                                              \
    dd = dpp_sum<0x142, 0xA>(dd);                                              \
    dd = dpp_sum<0x143, 0xC>(dd);                                              \
    dsc_##R = rdlane(dd, 63);                                                  \
  }

#define MV(R) e_p = fmaf(Mc##R, dsc_##R, e_p);

#define ACCT(R)                                    \
  {                                                \
    float et_ = rdlane(v_e, rbase + (R));          \
    accx = fmaf(et_, F4_##R.x, accx);              \
    accy = fmaf(et_, F4_##R.y, accy);              \
    accz = fmaf(et_, F4_##R.z, accz);              \
    accw = fmaf(et_, F4_##R.w, accw);              \
  }

  float Mc0, Mc1, Mc2, Mc3, Mc4, Mc5, Mc6, Mc7;
  float Mn0, Mn1, Mn2, Mn3, Mn4, Mn5, Mn6, Mn7;

  STAGE(0, 0);
  STAGE(1, 1);
  LOADM(0);
  Mc0 = Mn0; Mc1 = Mn1; Mc2 = Mn2; Mc3 = Mn3;
  Mc4 = Mn4; Mc5 = Mn5; Mc6 = Mn6; Mc7 = Mn7;
  asm volatile("s_waitcnt vmcnt(12)" ::: "memory");
  __builtin_amdgcn_s_barrier();
  __builtin_amdgcn_sched_barrier(0);

  // w' = w - e_j state: init -e_j (component j&3 of lane j>>2).
  const int jl4 = j >> 2, jc = j & 3;
  float w4x = (lane == jl4 && jc == 0) ? -1.f : 0.f;
  float w4y = (lane == jl4 && jc == 1) ? -1.f : 0.f;
  float w4z = (lane == jl4 && jc == 2) ? -1.f : 0.f;
  float w4w = (lane == jl4 && jc == 3) ? -1.f : 0.f;

#pragma unroll 1
  for (int c = 0; c < NCH; ++c) {
    const int cb = c & 1;
    const float* pF  = &ldsF[cb][0];
    const float* pF2 = pF + (rbase << 8);

    if (c + 1 < NCH) LOADM(c + 1);

    QROWS(DECLF)
    QROWS(DECLD)
    float e_p = 0.f;
    float accx = 0.f, accy = 0.f, accz = 0.f, accw = 0.f;

    float v_fjcol = 0.f;
    if (qr == 0) v_fjcol = pF[lm * 256 + j];

    QROWS(LOADF)
    __builtin_amdgcn_sched_barrier(0);
    QROWS(P0C)

    MV(0) MV(1) MV(2) MV(3) MV(4) MV(5) MV(6) MV(7)

    ldsE[cl][qr][lane] = e_p;
    __builtin_amdgcn_s_barrier();                 // bE
    float v_e = (ldsE[cl][0][lane] + ldsE[cl][1][lane]) +
                (ldsE[cl][2][lane] + ldsE[cl][3][lane]);

    if (qr == 0 && lane < 32) {
      float v = v_e + v_fjcol;
      u16 hi = f2bf(v);
      u16 lo = f2bf(v - bf2f(hi));
      pbh[(size_t)(c * RCH + lane) * Dsc] = hi;
      pbl[(size_t)(c * RCH + lane) * Dsc] = lo;
    }

    QROWS(ACCT)

    if (qr != 0) ldsA[cl][qr][lane] = make_float4(accx, accy, accz, accw);
    __builtin_amdgcn_s_barrier();                 // bA
    if (qr == 0) {
      float4 a1 = ldsA[cl][1][lane], a2 = ldsA[cl][2][lane],
             a3 = ldsA[cl][3][lane];
      accx += a1.x + a2.x + a3.x; accy += a1.y + a2.y + a3.y;
      accz += a1.z + a2.z + a3.z; accw += a1.w + a2.w + a3.w;
      w4x = fmaf(-LR, accx, w4x); w4y = fmaf(-LR, accy, w4y);
      w4z = fmaf(-LR, accz, w4z); w4w = fmaf(-LR, accw, w4w);
      ldsW[cl][lane] = make_float4(w4x, w4y, w4z, w4w);
    }

    if (c + 2 < NCH) {
      STAGE(cb, c + 2);
      asm volatile("s_waitcnt vmcnt(12)" ::: "memory");
    } else {
      asm volatile("s_waitcnt vmcnt(0)" ::: "memory");
    }
    __builtin_amdgcn_s_barrier();                 // bFinal
    if (qr != 0) {
      float4 wp = ldsW[cl][lane];
      w4x = wp.x; w4y = wp.y; w4z = wp.z; w4w = wp.w;
    }
    Mc0 = Mn0; Mc1 = Mn1; Mc2 = Mn2; Mc3 = Mn3;
    Mc4 = Mn4; Mc5 = Mn5; Mc6 = Mn6; Mc7 = Mn7;
    __builtin_amdgcn_sched_barrier(0);
  }
#undef ACCT
#undef MV
#undef P0C
#undef LOADF
#undef DECLD
#undef DECLF
#undef LOADM
#undef STAGE
}

extern "C" void kernel_launch(void* const* d_in, const int* in_sizes, int n_in,
                              void* d_out, int out_size, void* d_ws, size_t ws_size,
                              hipStream_t stream) {
  const float* x  = (const float*)d_in[0];  // (B,S,D)
  const float* Wd = (const float*)d_in[1];  // (D,Ds)
  const float* bd = (const float*)d_in[2];  // (Ds)
  const float* Wu = (const float*)d_in[3];  // (Ds,D)
  const float* bu = (const float*)d_in[4];  // (D)
  float* out = (float*)d_out;               // (B,S,D)

  const int M = Bc * Sc;  // 8192

  // Workspace layout:
  float* feat    = (float*)d_ws;                           // 8 MB
  float* MTg     = feat + (size_t)Bc * Sc * Dsc;           // 1 MB
  u16*   predsHi = (u16*)(MTg + (size_t)Bc * NCH * 1024);  // 4 MB
  u16*   predsLo = predsHi + (size_t)Bc * Sc * Dsc;        // 4 MB
  u16*   wuT     = predsLo + (size_t)Bc * Sc * Dsc;        // 0.5 MB [D][Ds]

  // Wu [Ds][D] fp32 -> wuT [D][Ds] bf16.
  castT_bf16<<<dim3(Dsc / 32, Dc / 32), dim3(256), 0, stream>>>(
      Wu, wuT, Dsc, Dc);

  // feat = x @ W_down + b_down   (fp32, bit-exact for the scan; M=8192,
  // N=256, K=1024)
  gemm_bias<<<dim3(M / 64, Dsc / 64), dim3(256), 0, stream>>>(
      x, Wd, bd, nullptr, feat, M, Dsc, Dc);

  // per-chunk M = (I+L)^{-1} (fp32, parallel)
  gram_inv<<<dim3(Bc * NCH), dim3(256), 0, stream>>>(feat, MTg);

  // chunked scan -> preds hi/lo bf16  (512 blocks x 8 waves; 4 waves/SIMD)
  ttt_scan<<<dim3(Bc * Dsc / 2), dim3(512), 0, stream>>>(
      feat, MTg, predsHi, predsLo);

  // out = (predsHi+predsLo) @ W_up + b_up + x  (MFMA bf16; M=8192, N=1024,
  // K=256)
  gemm_bf16_split<<<dim3(M / 64, Dc / 64), dim3(256), 0, stream>>>(
      predsHi, predsLo, wuT, bu, x, out, M, Dc, Dsc);
}

// Round 18
// 213.342 us; speedup vs baseline: 1.5864x; 1.1704x over previous
//
#include <hip/hip_runtime.h>

#define LR 0.01f

// Problem constants (from reference setup_inputs): B=4, S=2048, D=1024, Ds=256
constexpr int Bc  = 4;
constexpr int Sc  = 2048;
constexpr int Dc  = 1024;
constexpr int Dsc = 256;

typedef unsigned short u16;
typedef __attribute__((ext_vector_type(8))) short bf16x8;
typedef __attribute__((ext_vector_type(4))) float f32x4;

__device__ __forceinline__ u16 f2bf(float f) {
  unsigned u = __float_as_uint(f);
  unsigned r = (u + 0x7fff + ((u >> 16) & 1)) >> 16;  // round-to-nearest-even
  return (u16)r;
}
__device__ __forceinline__ float bf2f(u16 h) {
  return __uint_as_float((unsigned)h << 16);
}

__device__ __forceinline__ void async_cp16(const void* g, void* l) {
  __builtin_amdgcn_global_load_lds(
      (const __attribute__((address_space(1))) unsigned int*)g,
      (__attribute__((address_space(3))) unsigned int*)l, 16, 0, 0);
}

// ---------------------------------------------------------------------------
// v19: GEMM1 also moved to MFMA via DOUBLE hi/lo split (x and Wd both split;
// 3-term product, lo*lo dropped at 2^-16 rel). feat rel err ~1e-5 (200x
// better than v17's failed single-bf16 feat) -> recurrence-amplified error
// contribution <1 absmax. GEMM2 unchanged from v18 (passed @ absmax 16).
// Replaces the ~60us fp32 gemm1 with ~11us cast + ~15us MFMA gemm.
// ---------------------------------------------------------------------------

// Elementwise fp32 -> (hi, lo) bf16 split.
__global__ __launch_bounds__(256) void cast_split(const float* __restrict__ in,
                                                  u16* __restrict__ hi,
                                                  u16* __restrict__ lo) {
  int i = (blockIdx.x * 256 + threadIdx.x) * 4;
  float4 v = *(const float4*)&in[i];
  ushort4 h, l;
  h.x = f2bf(v.x); l.x = f2bf(v.x - bf2f(h.x));
  h.y = f2bf(v.y); l.y = f2bf(v.y - bf2f(h.y));
  h.z = f2bf(v.z); l.z = f2bf(v.z - bf2f(h.z));
  h.w = f2bf(v.w); l.w = f2bf(v.w - bf2f(h.w));
  *(ushort4*)&hi[i] = h;
  *(ushort4*)&lo[i] = l;
}

// W [K][N] fp32 -> WT [N][K] bf16 single (for Wu).
__global__ __launch_bounds__(256) void castT_bf16(const float* __restrict__ W,
                                                  u16* __restrict__ WT,
                                                  int K, int N) {
  __shared__ float t[32][33];
  const int bk = blockIdx.x * 32, bn = blockIdx.y * 32;
  const int tx = threadIdx.x & 31, ty = threadIdx.x >> 5;
  for (int r = ty; r < 32; r += 8) t[r][tx] = W[(size_t)(bk + r) * N + bn + tx];
  __syncthreads();
  for (int r = ty; r < 32; r += 8)
    WT[(size_t)(bn + r) * K + bk + tx] = f2bf(t[tx][r]);
}

// W [K][N] fp32 -> WT hi/lo [N][K] bf16 pair (for Wd).
__global__ __launch_bounds__(256) void castT_split(const float* __restrict__ W,
                                                   u16* __restrict__ WThi,
                                                   u16* __restrict__ WTlo,
                                                   int K, int N) {
  __shared__ float t[32][33];
  const int bk = blockIdx.x * 32, bn = blockIdx.y * 32;
  const int tx = threadIdx.x & 31, ty = threadIdx.x >> 5;
  for (int r = ty; r < 32; r += 8) t[r][tx] = W[(size_t)(bk + r) * N + bn + tx];
  __syncthreads();
  for (int r = ty; r < 32; r += 8) {
    float v = t[tx][r];
    u16 h = f2bf(v);
    WThi[(size_t)(bn + r) * K + bk + tx] = h;
    WTlo[(size_t)(bn + r) * K + bk + tx] = f2bf(v - bf2f(h));
  }
}

// ---------------------------------------------------------------------------
// 3-term split MFMA GEMM: C = (Ah+Al)@(Bh+Bl) + bias, A hi/lo bf16 [M][K],
// B hi/lo TRANSPOSED bf16 [N][K]. 64x64 tile, BK=32, 4 waves x 32x32
// quadrant, 12 mfma_f32_16x16x32_bf16 per K-step (hh, hl, lh).
// Frag/stage structure identical to the verified gemm_bf16_split.
// ---------------------------------------------------------------------------
__global__ __launch_bounds__(256) void gemm_bf16_split3(
    const u16* __restrict__ Ahi, const u16* __restrict__ Alo,
    const u16* __restrict__ BThi, const u16* __restrict__ BTlo,
    const float* __restrict__ bias, float* __restrict__ C,
    int M, int N, int K) {
  constexpr int BK = 32;
  __shared__ u16 sAh[2][64 * BK];
  __shared__ u16 sAl[2][64 * BK];
  __shared__ u16 sBh[2][64 * BK];
  __shared__ u16 sBl[2][64 * BK];

  const int wv = threadIdx.x >> 6, lane = threadIdx.x & 63;
  const int bm = blockIdx.x * 64, bn = blockIdx.y * 64;
  const int qm = (wv >> 1) * 32, qn = (wv & 1) * 32;
  const int lr = lane & 15, lk = lane >> 4;

  const int srow = lane >> 2;
  const int skp  = (lane & 3) * 8;
  const int NKS = K / BK;

#define GSTAGE(BUF, KS)                                                   \
  {                                                                       \
    async_cp16(Ahi + (size_t)(bm + wv * 16 + srow) * K + (KS)*BK + skp,   \
               &sAh[BUF][wv * 512]);                                      \
    async_cp16(Alo + (size_t)(bm + wv * 16 + srow) * K + (KS)*BK + skp,   \
               &sAl[BUF][wv * 512]);                                      \
    async_cp16(BThi + (size_t)(bn + wv * 16 + srow) * K + (KS)*BK + skp,  \
               &sBh[BUF][wv * 512]);                                      \
    async_cp16(BTlo + (size_t)(bn + wv * 16 + srow) * K + (KS)*BK + skp,  \
               &sBl[BUF][wv * 512]);                                      \
  }

  f32x4 acc00 = {0.f, 0.f, 0.f, 0.f}, acc01 = {0.f, 0.f, 0.f, 0.f};
  f32x4 acc10 = {0.f, 0.f, 0.f, 0.f}, acc11 = {0.f, 0.f, 0.f, 0.f};

  GSTAGE(0, 0);
  GSTAGE(1, 1);
  asm volatile("s_waitcnt vmcnt(4)" ::: "memory");  // stage-0's 4 ops done
  __builtin_amdgcn_s_barrier();

  for (int ks = 0; ks < NKS; ++ks) {
    const int cb = ks & 1;
    bf16x8 ah0 = *(const bf16x8*)&sAh[cb][(qm + lr) * BK + lk * 8];
    bf16x8 ah1 = *(const bf16x8*)&sAh[cb][(qm + 16 + lr) * BK + lk * 8];
    bf16x8 al0 = *(const bf16x8*)&sAl[cb][(qm + lr) * BK + lk * 8];
    bf16x8 al1 = *(const bf16x8*)&sAl[cb][(qm + 16 + lr) * BK + lk * 8];
    bf16x8 bh0 = *(const bf16x8*)&sBh[cb][(qn + lr) * BK + lk * 8];
    bf16x8 bh1 = *(const bf16x8*)&sBh[cb][(qn + 16 + lr) * BK + lk * 8];
    bf16x8 bl0 = *(const bf16x8*)&sBl[cb][(qn + lr) * BK + lk * 8];
    bf16x8 bl1 = *(const bf16x8*)&sBl[cb][(qn + 16 + lr) * BK + lk * 8];
    // hh
    acc00 = __builtin_amdgcn_mfma_f32_16x16x32_bf16(ah0, bh0, acc00, 0, 0, 0);
    acc01 = __builtin_amdgcn_mfma_f32_16x16x32_bf16(ah0, bh1, acc01, 0, 0, 0);
    acc10 = __builtin_amdgcn_mfma_f32_16x16x32_bf16(ah1, bh0, acc10, 0, 0, 0);
    acc11 = __builtin_amdgcn_mfma_f32_16x16x32_bf16(ah1, bh1, acc11, 0, 0, 0);
    // hl
    acc00 = __builtin_amdgcn_mfma_f32_16x16x32_bf16(ah0, bl0, acc00, 0, 0, 0);
    acc01 = __builtin_amdgcn_mfma_f32_16x16x32_bf16(ah0, bl1, acc01, 0, 0, 0);
    acc10 = __builtin_amdgcn_mfma_f32_16x16x32_bf16(ah1, bl0, acc10, 0, 0, 0);
    acc11 = __builtin_amdgcn_mfma_f32_16x16x32_bf16(ah1, bl1, acc11, 0, 0, 0);
    // lh
    acc00 = __builtin_amdgcn_mfma_f32_16x16x32_bf16(al0, bh0, acc00, 0, 0, 0);
    acc01 = __builtin_amdgcn_mfma_f32_16x16x32_bf16(al0, bh1, acc01, 0, 0, 0);
    acc10 = __builtin_amdgcn_mfma_f32_16x16x32_bf16(al1, bh0, acc10, 0, 0, 0);
    acc11 = __builtin_amdgcn_mfma_f32_16x16x32_bf16(al1, bh1, acc11, 0, 0, 0);
    __builtin_amdgcn_s_barrier();
    if (ks + 2 < NKS) {
      GSTAGE(cb, ks + 2);
      asm volatile("s_waitcnt vmcnt(4)" ::: "memory");  // stage ks+1 done
    } else {
      asm volatile("s_waitcnt vmcnt(0)" ::: "memory");
    }
    __builtin_amdgcn_s_barrier();
  }

#define WRT(ACC, AR, BC)                                                 \
  {                                                                      \
    _Pragma("unroll")                                                    \
    for (int r = 0; r < 4; ++r) {                                        \
      int row = bm + qm + (AR) + lk * 4 + r;                             \
      int col = bn + qn + (BC) + lr;                                     \
      C[(size_t)row * N + col] = ACC[r] + bias[col];                     \
    }                                                                    \
  }
  WRT(acc00, 0, 0) WRT(acc01, 0, 16) WRT(acc10, 16, 0) WRT(acc11, 16, 16)
#undef WRT
#undef GSTAGE
}

// ---------------------------------------------------------------------------
// bf16 MFMA GEMM with HI/LO-split A only (v18, verified): C = (Ahi+Alo)@B
// + bias + resid.
// ---------------------------------------------------------------------------
__global__ __launch_bounds__(256) void gemm_bf16_split(
    const u16* __restrict__ Ahi, const u16* __restrict__ Alo,
    const u16* __restrict__ BT, const float* __restrict__ bias,
    const float* __restrict__ resid, float* __restrict__ C,
    int M, int N, int K) {
  constexpr int BK = 32;
  __shared__ u16 sAh[2][64 * BK];
  __shared__ u16 sAl[2][64 * BK];
  __shared__ u16 sB[2][64 * BK];

  const int wv = threadIdx.x >> 6, lane = threadIdx.x & 63;
  const int bm = blockIdx.x * 64, bn = blockIdx.y * 64;
  const int qm = (wv >> 1) * 32, qn = (wv & 1) * 32;
  const int lr = lane & 15, lk = lane >> 4;

  const int srow = lane >> 2;
  const int skp  = (lane & 3) * 8;
  const int NKS = K / BK;

#define GSTAGE(BUF, KS)                                                   \
  {                                                                       \
    async_cp16(Ahi + (size_t)(bm + wv * 16 + srow) * K + (KS)*BK + skp,   \
               &sAh[BUF][wv * 512]);                                      \
    async_cp16(Alo + (size_t)(bm + wv * 16 + srow) * K + (KS)*BK + skp,   \
               &sAl[BUF][wv * 512]);                                      \
    async_cp16(BT + (size_t)(bn + wv * 16 + srow) * K + (KS)*BK + skp,    \
               &sB[BUF][wv * 512]);                                       \
  }

  f32x4 acc00 = {0.f, 0.f, 0.f, 0.f}, acc01 = {0.f, 0.f, 0.f, 0.f};
  f32x4 acc10 = {0.f, 0.f, 0.f, 0.f}, acc11 = {0.f, 0.f, 0.f, 0.f};

  GSTAGE(0, 0);
  GSTAGE(1, 1);
  asm volatile("s_waitcnt vmcnt(3)" ::: "memory");
  __builtin_amdgcn_s_barrier();

  for (int ks = 0; ks < NKS; ++ks) {
    const int cb = ks & 1;
    bf16x8 ah0 = *(const bf16x8*)&sAh[cb][(qm + lr) * BK + lk * 8];
    bf16x8 ah1 = *(const bf16x8*)&sAh[cb][(qm + 16 + lr) * BK + lk * 8];
    bf16x8 al0 = *(const bf16x8*)&sAl[cb][(qm + lr) * BK + lk * 8];
    bf16x8 al1 = *(const bf16x8*)&sAl[cb][(qm + 16 + lr) * BK + lk * 8];
    bf16x8 b0  = *(const bf16x8*)&sB[cb][(qn + lr) * BK + lk * 8];
    bf16x8 b1  = *(const bf16x8*)&sB[cb][(qn + 16 + lr) * BK + lk * 8];
    acc00 = __builtin_amdgcn_mfma_f32_16x16x32_bf16(ah0, b0, acc00, 0, 0, 0);
    acc01 = __builtin_amdgcn_mfma_f32_16x16x32_bf16(ah0, b1, acc01, 0, 0, 0);
    acc10 = __builtin_amdgcn_mfma_f32_16x16x32_bf16(ah1, b0, acc10, 0, 0, 0);
    acc11 = __builtin_amdgcn_mfma_f32_16x16x32_bf16(ah1, b1, acc11, 0, 0, 0);
    acc00 = __builtin_amdgcn_mfma_f32_16x16x32_bf16(al0, b0, acc00, 0, 0, 0);
    acc01 = __builtin_amdgcn_mfma_f32_16x16x32_bf16(al0, b1, acc01, 0, 0, 0);
    acc10 = __builtin_amdgcn_mfma_f32_16x16x32_bf16(al1, b0, acc10, 0, 0, 0);
    acc11 = __builtin_amdgcn_mfma_f32_16x16x32_bf16(al1, b1, acc11, 0, 0, 0);
    __builtin_amdgcn_s_barrier();
    if (ks + 2 < NKS) {
      GSTAGE(cb, ks + 2);
      asm volatile("s_waitcnt vmcnt(3)" ::: "memory");
    } else {
      asm volatile("s_waitcnt vmcnt(0)" ::: "memory");
    }
    __builtin_amdgcn_s_barrier();
  }

#define WRT(ACC, AR, BC)                                                 \
  {                                                                      \
    _Pragma("unroll")                                                    \
    for (int r = 0; r < 4; ++r) {                                        \
      int row = bm + qm + (AR) + lk * 4 + r;                             \
      int col = bn + qn + (BC) + lr;                                     \
      float v = ACC[r] + bias[col];                                      \
      if (resid) v += resid[(size_t)row * N + col];                      \
      C[(size_t)row * N + col] = v;                                      \
    }                                                                    \
  }
  WRT(acc00, 0, 0) WRT(acc01, 0, 16) WRT(acc10, 16, 0) WRT(acc11, 16, 16)
#undef WRT
#undef GSTAGE
}

// ---------------------------------------------------------------------------
// Scan machinery (v16, verified @ ~152us): unchanged.
// ---------------------------------------------------------------------------

template <int CTRL, int RM>
__device__ __forceinline__ float dpp_sum(float v) {
  int moved = __builtin_amdgcn_update_dpp(0, __float_as_int(v), CTRL, RM, 0xF, false);
  return v + __int_as_float(moved);
}

__device__ __forceinline__ float rdlane(float v, int l) {
  return __int_as_float(__builtin_amdgcn_readlane(__float_as_int(v), l));
}

constexpr int RCH = 32;        // rows per chunk
constexpr int NCH = Sc / RCH;  // 64 chunks

// MTg[bc][s*32+t] = M[t][s], M = (I + L)^{-1}, L[t][s] = LR*dot(f_t,f_s) s<t
__global__ __launch_bounds__(256) void gram_inv(const float* __restrict__ feat,
                                                float* __restrict__ MTg) {
  const int bc = blockIdx.x;  // 0..B*NCH-1
  __shared__ float Fl[32 * 260];
  __shared__ float Gl[32 * 32];
  __shared__ float Ml[32 * 32];
  const float* src = feat + (size_t)bc * RCH * Dsc;
  for (int i = threadIdx.x; i < 32 * 256; i += 256) {
    int r = i >> 8, cc = i & 255;
    Fl[r * 260 + cc] = src[i];
  }
  __syncthreads();
#pragma unroll
  for (int k2 = 0; k2 < 4; ++k2) {
    int idx = threadIdx.x + (k2 << 8);
    int t = idx >> 5, s = idx & 31;
    float sum = 0.f;
    if (s < t) {
      const float4* ft = (const float4*)&Fl[t * 260];
      const float4* fs = (const float4*)&Fl[s * 260];
#pragma unroll
      for (int i = 0; i < 64; ++i) {
        float4 a = ft[i], b = fs[i];
        sum = fmaf(a.x, b.x, sum); sum = fmaf(a.y, b.y, sum);
        sum = fmaf(a.z, b.z, sum); sum = fmaf(a.w, b.w, sum);
      }
      sum *= LR;
    }
    Gl[idx] = sum;
  }
  __syncthreads();
  if (threadIdx.x < 32) {
    const int s = threadIdx.x;
    for (int t = 0; t < 32; ++t) {
      float sum = 0.f;
      for (int u = 0; u < t; ++u)
        sum = fmaf(Gl[t * 32 + u], Ml[u * 32 + s], sum);
      Ml[t * 32 + s] = ((t == s) ? 1.f : 0.f) - sum;
    }
  }
  __syncthreads();
  float* dst = MTg + (size_t)bc * 1024;
#pragma unroll
  for (int k2 = 0; k2 < 4; ++k2) {
    int idx = threadIdx.x + (k2 << 8);
    int s = idx >> 5, t = idx & 31;
    dst[idx] = Ml[t * 32 + s];  // transposed store
  }
}

__device__ __forceinline__ void async_copy16f(const float* g, float* l) {
  __builtin_amdgcn_global_load_lds(
      (const __attribute__((address_space(1))) unsigned int*)g,
      (__attribute__((address_space(3))) unsigned int*)l, 16, 0, 0);
}

// Per-wave local rows 0..7.
#define QROWS(X) X(0) X(1) X(2) X(3) X(4) X(5) X(6) X(7)

__global__ __launch_bounds__(512, 4) void ttt_scan(
    const float* __restrict__ feat, const float* __restrict__ MTg,
    u16* __restrict__ predsHi, u16* __restrict__ predsLo) {
  const int lane = threadIdx.x & 63;
  const int wv   = threadIdx.x >> 6;   // 0..7
  const int lm   = lane & 31;
  const int cl   = wv & 1;             // column within block
  const int qr   = wv >> 1;            // row quarter (8 rows each)
  const int rbase = qr << 3;

  // XCD-locality swizzle for 512 blocks (bijective).
  const int bi  = blockIdx.x;                    // 0..511
  const int xcd = bi & 7;
  const int b   = xcd >> 1;                      // 0..3
  const int q   = ((bi >> 3) << 1) | (xcd & 1);  // 0..127 col-pair within b
  const int j   = (q << 1) | cl;                 // 0..255

  __shared__ float  ldsF[2][RCH * Dsc];  // 64 KB
  __shared__ float  ldsE[2][4][64];      // 2 KB  e-partial exchange
  __shared__ float4 ldsA[2][4][64];      // 8 KB  acc partials (qr 1..3 used)
  __shared__ float4 ldsW[2][64];         // 2 KB  w' publish (qr0 -> others)

  const float* fb0 = feat + (size_t)b * Sc * Dsc;
  const float* Mg  = MTg + (size_t)b * NCH * 1024;
  u16* pbh = predsHi + (size_t)b * Sc * Dsc + j;
  u16* pbl = predsLo + (size_t)b * Sc * Dsc + j;

#define STAGE(BUF, C0)                                                     \
  {                                                                        \
    _Pragma("unroll")                                                      \
    for (int r_ = 0; r_ < 4; ++r_) {                                       \
      const int row_ = (wv << 2) | r_;                                     \
      async_copy16f(fb0 + (size_t)((C0) * RCH + row_) * Dsc + (lane << 2), \
                    &ldsF[BUF][row_ * Dsc]);                               \
    }                                                                      \
  }

#define LOADM(C1)                                          \
  {                                                        \
    const float* mp_ = Mg + (size_t)(C1) * 1024 + lm;      \
    Mn0 = mp_[(rbase + 0) * 32]; Mn1 = mp_[(rbase + 1) * 32]; \
    Mn2 = mp_[(rbase + 2) * 32]; Mn3 = mp_[(rbase + 3) * 32]; \
    Mn4 = mp_[(rbase + 4) * 32]; Mn5 = mp_[(rbase + 5) * 32]; \
    Mn6 = mp_[(rbase + 6) * 32]; Mn7 = mp_[(rbase + 7) * 32]; \
  }

#define DECLF(R) float4 F4_##R;
#define DECLD(R) float dsc_##R;

#define LOADF(R) F4_##R = *(const float4*)&pF2[(R) * 256 + (lane << 2)];

#define P0C(R)                                                                 \
  {                                                                            \
    float dd = fmaf(F4_##R.y, w4y, F4_##R.x * w4x) +                           \
               fmaf(F4_##R.w, w4w, F4_##R.z * w4z);                            \
    dd = dpp_sum<0x111, 0xF>(dd);                                              \
    dd = dpp_sum<0x112, 0xF>(dd);                                              \
    dd = dpp_sum<0x114, 0xF>(dd);                                              \
    dd = dpp_sum<0x118, 0xF>(dd);                                              \
    dd = dpp_sum<0x142, 0xA>(dd);                                              \
    dd = dpp_sum<0x143, 0xC>(dd);                                              \
    dsc_##R = rdlane(dd, 63);                                                  \
  }

#define MV(R) e_p = fmaf(Mc##R, dsc_##R, e_p);

#define ACCT(R)                                    \
  {                                                \
    float et_ = rdlane(v_e, rbase + (R));          \
    accx = fmaf(et_, F4_##R.x, accx);              \
    accy = fmaf(et_, F4_##R.y, accy);              \
    accz = fmaf(et_, F4_##R.z, accz);              \
    accw = fmaf(et_, F4_##R.w, accw);              \
  }

  float Mc0, Mc1, Mc2, Mc3, Mc4, Mc5, Mc6, Mc7;
  float Mn0, Mn1, Mn2, Mn3, Mn4, Mn5, Mn6, Mn7;

  STAGE(0, 0);
  STAGE(1, 1);
  LOADM(0);
  Mc0 = Mn0; Mc1 = Mn1; Mc2 = Mn2; Mc3 = Mn3;
  Mc4 = Mn4; Mc5 = Mn5; Mc6 = Mn6; Mc7 = Mn7;
  asm volatile("s_waitcnt vmcnt(12)" ::: "memory");
  __builtin_amdgcn_s_barrier();
  __builtin_amdgcn_sched_barrier(0);

  // w' = w - e_j state: init -e_j (component j&3 of lane j>>2).
  const int jl4 = j >> 2, jc = j & 3;
  float w4x = (lane == jl4 && jc == 0) ? -1.f : 0.f;
  float w4y = (lane == jl4 && jc == 1) ? -1.f : 0.f;
  float w4z = (lane == jl4 && jc == 2) ? -1.f : 0.f;
  float w4w = (lane == jl4 && jc == 3) ? -1.f : 0.f;

#pragma unroll 1
  for (int c = 0; c < NCH; ++c) {
    const int cb = c & 1;
    const float* pF  = &ldsF[cb][0];
    const float* pF2 = pF + (rbase << 8);

    if (c + 1 < NCH) LOADM(c + 1);

    QROWS(DECLF)
    QROWS(DECLD)
    float e_p = 0.f;
    float accx = 0.f, accy = 0.f, accz = 0.f, accw = 0.f;

    float v_fjcol = 0.f;
    if (qr == 0) v_fjcol = pF[lm * 256 + j];

    QROWS(LOADF)
    __builtin_amdgcn_sched_barrier(0);
    QROWS(P0C)

    MV(0) MV(1) MV(2) MV(3) MV(4) MV(5) MV(6) MV(7)

    ldsE[cl][qr][lane] = e_p;
    __builtin_amdgcn_s_barrier();                 // bE
    float v_e = (ldsE[cl][0][lane] + ldsE[cl][1][lane]) +
                (ldsE[cl][2][lane] + ldsE[cl][3][lane]);

    if (qr == 0 && lane < 32) {
      float v = v_e + v_fjcol;
      u16 hi = f2bf(v);
      u16 lo = f2bf(v - bf2f(hi));
      pbh[(size_t)(c * RCH + lane) * Dsc] = hi;
      pbl[(size_t)(c * RCH + lane) * Dsc] = lo;
    }

    QROWS(ACCT)

    if (qr != 0) ldsA[cl][qr][lane] = make_float4(accx, accy, accz, accw);
    __builtin_amdgcn_s_barrier();                 // bA
    if (qr == 0) {
      float4 a1 = ldsA[cl][1][lane], a2 = ldsA[cl][2][lane],
             a3 = ldsA[cl][3][lane];
      accx += a1.x + a2.x + a3.x; accy += a1.y + a2.y + a3.y;
      accz += a1.z + a2.z + a3.z; accw += a1.w + a2.w + a3.w;
      w4x = fmaf(-LR, accx, w4x); w4y = fmaf(-LR, accy, w4y);
      w4z = fmaf(-LR, accz, w4z); w4w = fmaf(-LR, accw, w4w);
      ldsW[cl][lane] = make_float4(w4x, w4y, w4z, w4w);
    }

    if (c + 2 < NCH) {
      STAGE(cb, c + 2);
      asm volatile("s_waitcnt vmcnt(12)" ::: "memory");
    } else {
      asm volatile("s_waitcnt vmcnt(0)" ::: "memory");
    }
    __builtin_amdgcn_s_barrier();                 // bFinal
    if (qr != 0) {
      float4 wp = ldsW[cl][lane];
      w4x = wp.x; w4y = wp.y; w4z = wp.z; w4w = wp.w;
    }
    Mc0 = Mn0; Mc1 = Mn1; Mc2 = Mn2; Mc3 = Mn3;
    Mc4 = Mn4; Mc5 = Mn5; Mc6 = Mn6; Mc7 = Mn7;
    __builtin_amdgcn_sched_barrier(0);
  }
#undef ACCT
#undef MV
#undef P0C
#undef LOADF
#undef DECLD
#undef DECLF
#undef LOADM
#undef STAGE
}

extern "C" void kernel_launch(void* const* d_in, const int* in_sizes, int n_in,
                              void* d_out, int out_size, void* d_ws, size_t ws_size,
                              hipStream_t stream) {
  const float* x  = (const float*)d_in[0];  // (B,S,D)
  const float* Wd = (const float*)d_in[1];  // (D,Ds)
  const float* bd = (const float*)d_in[2];  // (Ds)
  const float* Wu = (const float*)d_in[3];  // (Ds,D)
  const float* bu = (const float*)d_in[4];  // (D)
  float* out = (float*)d_out;               // (B,S,D)

  const int M = Bc * Sc;  // 8192

  // Workspace layout (~43.5 MB with aliasing):
  u16*   xhi   = (u16*)d_ws;                         // 16.8 MB
  u16*   xlo   = xhi + (size_t)M * Dc;               // 16.8 MB
  float* feat  = (float*)(xlo + (size_t)M * Dc);     // 8.4 MB
  u16*   wdThi = (u16*)(feat + (size_t)M * Dsc);     // 0.5 MB [Ds][D]
  u16*   wdTlo = wdThi + (size_t)Dc * Dsc;           // 0.5 MB
  u16*   wuT   = wdTlo + (size_t)Dc * Dsc;           // 0.5 MB [D][Ds]
  // Aliased into xhi's region (xhi/xlo dead after gemm1; stream-ordered):
  float* MTg     = (float*)xhi;                      // 1 MB
  u16*   predsHi = (u16*)(MTg + (size_t)Bc * NCH * 1024);  // 4.2 MB
  u16*   predsLo = predsHi + (size_t)Bc * Sc * Dsc;        // 4.2 MB

  // Casts: x -> hi/lo bf16; Wd -> transposed hi/lo; Wu -> transposed bf16.
  cast_split<<<dim3(M * Dc / 1024), dim3(256), 0, stream>>>(x, xhi, xlo);
  castT_split<<<dim3(Dc / 32, Dsc / 32), dim3(256), 0, stream>>>(
      Wd, wdThi, wdTlo, Dc, Dsc);
  castT_bf16<<<dim3(Dsc / 32, Dc / 32), dim3(256), 0, stream>>>(
      Wu, wuT, Dsc, Dc);

  // feat = (xhi+xlo) @ (wdhi+wdlo) + b_down  (3-term MFMA; M=8192, N=256,
  // K=1024; feat rel err ~1e-5)
  gemm_bf16_split3<<<dim3(M / 64, Dsc / 64), dim3(256), 0, stream>>>(
      xhi, xlo, wdThi, wdTlo, bd, feat, M, Dsc, Dc);

  // per-chunk M = (I+L)^{-1} (fp32, parallel)
  gram_inv<<<dim3(Bc * NCH), dim3(256), 0, stream>>>(feat, MTg);

  // chunked scan -> preds hi/lo bf16  (512 blocks x 8 waves; 4 waves/SIMD)
  ttt_scan<<<dim3(Bc * Dsc / 2), dim3(512), 0, stream>>>(
      feat, MTg, predsHi, predsLo);

  // out = (predsHi+predsLo) @ W_up + b_up + x  (MFMA bf16; M=8192, N=1024,
  // K=256)
  gemm_bf16_split<<<dim3(M / 64, Dc / 64), dim3(256), 0, stream>>>(
      predsHi, predsLo, wuT, bu, x, out, M, Dc, Dsc);
}